// Round 7
// baseline (1020.780 us; speedup 1.0000x reference)
//
#include <hip/hip_runtime.h>

typedef _Float16 f16;
typedef _Float16 f16x8 __attribute__((ext_vector_type(8)));
typedef float f32x16 __attribute__((ext_vector_type(16)));

#define MFMA(a, b, c) __builtin_amdgcn_mfma_f32_32x32x16_f16(a, b, c, 0, 0, 0)

__device__ __forceinline__ void gload_lds16(const f16* g, f16* l) {
    __builtin_amdgcn_global_load_lds(
        (const __attribute__((address_space(1))) unsigned int*)g,
        (__attribute__((address_space(3))) unsigned int*)l, 16, 0, 0);
}

// ---------------- preprocessing: two-level counting sort ----------------
// bucket = dst >> 8 (256 nodes per bucket). Assumes N <= 65536 (here N=50000).

#define NBMAX 256
#define CHUNK 8192
#define CAP   8192

// Per-block LDS histograms -> one global atomic per (block,bucket).
__global__ __launch_bounds__(256) void bin_count(
        const int* __restrict__ dst, const int* __restrict__ clen,
        int* __restrict__ gbc, int* __restrict__ ghist, int E, int n, int chn) {
    __shared__ int bc[NBMAX];
    __shared__ int ch[9];
    int tid = threadIdx.x;
    bc[tid] = 0;
    if (tid < 9) ch[tid] = 0;
    __syncthreads();
    int e0 = blockIdx.x * CHUNK, e1 = min(e0 + CHUNK, E);
    for (int i = e0 + tid; i < e1; i += 256)
        atomicAdd(&bc[dst[i] >> 8], 1);
    int n0 = blockIdx.x * chn, n1 = min(n0 + chn, n);
    for (int i = n0 + tid; i < n1; i += 256) {
        int l = clen[i]; l = max(0, min(8, l));
        atomicAdd(&ch[l], 1);
    }
    __syncthreads();
    if (bc[tid]) atomicAdd(&gbc[tid], bc[tid]);
    if (tid < 9 && ch[tid]) atomicAdd(&ghist[tid], ch[tid]);
}

// Exclusive scan of 196 bucket counts + 9 clen bins. One tiny block.
__global__ __launch_bounds__(256) void scan_small(
        const int* __restrict__ gbc, int* __restrict__ gbase,
        const int* __restrict__ ghist, int* __restrict__ chbase, int nb, int E) {
    __shared__ int s[NBMAX];
    int tid = threadIdx.x;
    int v = (tid < nb) ? gbc[tid] : 0;
    s[tid] = v;
    __syncthreads();
    for (int off = 1; off < 256; off <<= 1) {
        int u = (tid >= off) ? s[tid - off] : 0;
        __syncthreads();
        s[tid] += u;
        __syncthreads();
    }
    if (tid <= nb) gbase[tid] = (tid < nb) ? s[tid] - v : E;
    if (tid == 0) {
        int run = 0;
        for (int i = 0; i < 9; ++i) { int c = ghist[i]; chbase[i] = run; run += c; }
    }
}

// Bucket-grouped scatter with per-block reservations (contiguous runs, no
// per-edge global atomics). Also builds perm/plen the same way.
__global__ __launch_bounds__(256) void bin_scatter(
        const int* __restrict__ src, const int* __restrict__ dst,
        const int* __restrict__ clen,
        const int* __restrict__ gbase, int* __restrict__ gfill,
        const int* __restrict__ chbase, int* __restrict__ chfill,
        int2* __restrict__ binned, int* __restrict__ perm, int* __restrict__ plen,
        int E, int n, int chn) {
    __shared__ int bc[NBMAX], bb[NBMAX];
    __shared__ int cc[9], cb[9];
    int tid = threadIdx.x;
    bc[tid] = 0;
    if (tid < 9) cc[tid] = 0;
    __syncthreads();
    int e0 = blockIdx.x * CHUNK, e1 = min(e0 + CHUNK, E);
    for (int i = e0 + tid; i < e1; i += 256)
        atomicAdd(&bc[dst[i] >> 8], 1);
    int n0 = blockIdx.x * chn, n1 = min(n0 + chn, n);
    for (int i = n0 + tid; i < n1; i += 256) {
        int l = clen[i]; l = max(0, min(8, l));
        atomicAdd(&cc[l], 1);
    }
    __syncthreads();
    {
        int c = bc[tid];
        bb[tid] = c ? gbase[tid] + atomicAdd(&gfill[tid], c) : 0;
        bc[tid] = 0;
    }
    if (tid < 9) {
        int c = cc[tid];
        cb[tid] = c ? chbase[tid] + atomicAdd(&chfill[tid], c) : 0;
        cc[tid] = 0;
    }
    __syncthreads();
    for (int i = e0 + tid; i < e1; i += 256) {
        int d = dst[i], b = d >> 8;
        int p = bb[b] + atomicAdd(&bc[b], 1);
        binned[p] = make_int2(src[i], d);
    }
    for (int i = n0 + tid; i < n1; i += 256) {
        int l = clen[i]; l = max(0, min(8, l));
        int p = cb[l] + atomicAdd(&cc[l], 1);
        perm[p] = i;
        plen[p] = l;
    }
}

// One block per bucket: per-node counts+scan in LDS -> row_ptr/inv_s; scatter
// edges inside LDS, stream out coalesced.
__global__ __launch_bounds__(256) void csr_build(
        const int2* __restrict__ binned, const int* __restrict__ gbase,
        int* __restrict__ row_ptr, float* __restrict__ inv_s,
        int* __restrict__ ew, int E, int n) {
    __shared__ int cnt[256], base[256], fill[256];
    __shared__ int ebuf[CAP];
    int tid = threadIdx.x, b = blockIdx.x;
    int e0 = gbase[b], e1 = gbase[b + 1], sz = e1 - e0;
    cnt[tid] = 0;
    __syncthreads();
    for (int i = e0 + tid; i < e1; i += 256)
        atomicAdd(&cnt[binned[i].y & 255], 1);
    __syncthreads();
    int v = cnt[tid];
    base[tid] = v;
    __syncthreads();
    for (int off = 1; off < 256; off <<= 1) {
        int u = (tid >= off) ? base[tid - off] : 0;
        __syncthreads();
        base[tid] += u;
        __syncthreads();
    }
    int ex = base[tid] - v;
    base[tid] = ex;
    fill[tid] = 0;
    int node = b * 256 + tid;
    if (node < n) {
        row_ptr[node] = e0 + ex;
        inv_s[node] = rsqrtf((float)(v + 1));
    }
    if (b == 0 && tid == 0) row_ptr[n] = E;
    __syncthreads();
    for (int i = e0 + tid; i < e1; i += 256) {
        int2 q = binned[i];
        int lo = q.y & 255;
        int p = base[lo] + atomicAdd(&fill[lo], 1);
        if (p < CAP) ebuf[p] = q.x; else ew[e0 + p] = q.x;
    }
    __syncthreads();
    int lim = min(sz, CAP);
    for (int p = tid; p < lim; p += 256) ew[e0 + p] = ebuf[p];
}

// LDS-tiled transpose-split: W[k][256] -> Wt[n][k] hi/lo, coalesced both sides.
// blocks 0..127: rW tiles; 128..143: gW tiles.
__global__ __launch_bounds__(256) void pre_trans(
        const float* __restrict__ gW, f16* __restrict__ Wth, f16* __restrict__ Wtl,
        const float* __restrict__ rW, f16* __restrict__ Rth, f16* __restrict__ Rtl) {
    int b = blockIdx.x;
    __shared__ f16 Th[64][68], Tl[64][68];
    const float* src; f16 *dh, *dl; int K, k0, n0;
    if (b < 128) { src = rW; dh = Rth; dl = Rtl; K = 2048; k0 = (b >> 2) * 64; n0 = (b & 3) * 64; }
    else { int bb = b - 128; src = gW; dh = Wth; dl = Wtl; K = 256; k0 = (bb >> 2) * 64; n0 = (bb & 3) * 64; }
    int c = threadIdx.x & 63, r0 = threadIdx.x >> 6;
    for (int rr = r0; rr < 64; rr += 4) {
        float v = src[(size_t)(k0 + rr) * 256 + n0 + c];
        f16 h = (f16)v;
        Th[rr][c] = h; Tl[rr][c] = (f16)(v - (float)h);
    }
    __syncthreads();
    int k = threadIdx.x & 63, nr0 = threadIdx.x >> 6;
    for (int nn = nr0; nn < 64; nn += 4) {
        size_t oidx = (size_t)(n0 + nn) * K + k0 + k;
        dh[oidx] = Th[k][nn];
        dl[oidx] = Tl[k][nn];
    }
}

// ---------------- aggregation: 2 waves per node, 8-deep, LDS combine --------

union H4 { f16 f[4]; ushort4 u; };

__global__ __launch_bounds__(512, 4) void agg_split(const float* __restrict__ X,
        const int* __restrict__ ew, const int* __restrict__ rp,
        const float* __restrict__ invs, f16* __restrict__ ohi, f16* __restrict__ olo, int n) {
    __shared__ float part[4][256];
    int w = threadIdx.x >> 6, lane = threadIdx.x & 63;
    int local = w >> 1, half = w & 1;
    int node = blockIdx.x * 4 + local;
    bool active = node < n;
    float4 acc = make_float4(0.f, 0.f, 0.f, 0.f);
    float si = 0.f;
    if (active) {
        si = invs[node];
        int e0 = rp[node], e1 = rp[node + 1];
        int mid = e0 + ((e1 - e0 + 1) >> 1);
        int lo = half ? mid : e0;
        int hi = half ? e1 : mid;
        if (!half) {
            float4 a = *((const float4*)(X + (size_t)node * 256) + lane);
            acc = make_float4(a.x * si, a.y * si, a.z * si, a.w * si);
        }
        int e = lo;
        for (; e + 8 <= hi; e += 8) {
            int q[8]; float ws[8]; float4 v[8];
            #pragma unroll
            for (int u = 0; u < 8; ++u) q[u] = ew[e + u];
            #pragma unroll
            for (int u = 0; u < 8; ++u) ws[u] = invs[q[u]];
            #pragma unroll
            for (int u = 0; u < 8; ++u) v[u] = *((const float4*)(X + (size_t)q[u] * 256) + lane);
            #pragma unroll
            for (int u = 0; u < 8; ++u) {
                acc.x = fmaf(ws[u], v[u].x, acc.x); acc.y = fmaf(ws[u], v[u].y, acc.y);
                acc.z = fmaf(ws[u], v[u].z, acc.z); acc.w = fmaf(ws[u], v[u].w, acc.w);
            }
        }
        for (; e < hi; ++e) {
            int q = ew[e];
            float wq = invs[q];
            float4 v = *((const float4*)(X + (size_t)q * 256) + lane);
            acc.x = fmaf(wq, v.x, acc.x); acc.y = fmaf(wq, v.y, acc.y);
            acc.z = fmaf(wq, v.z, acc.z); acc.w = fmaf(wq, v.w, acc.w);
        }
    }
    if (half) *(float4*)&part[local][lane * 4] = acc;
    __syncthreads();
    if (!half && active) {
        float4 o = *(const float4*)&part[local][lane * 4];
        float v0 = si * (acc.x + o.x), v1 = si * (acc.y + o.y);
        float v2 = si * (acc.z + o.z), v3 = si * (acc.w + o.w);
        H4 hh, ll;
        f16 h;
        h = (f16)v0; hh.f[0] = h; ll.f[0] = (f16)(v0 - (float)h);
        h = (f16)v1; hh.f[1] = h; ll.f[1] = (f16)(v1 - (float)h);
        h = (f16)v2; hh.f[2] = h; ll.f[2] = (f16)(v2 - (float)h);
        h = (f16)v3; hh.f[3] = h; ll.f[3] = (f16)(v3 - (float)h);
        size_t off = (size_t)node * 256 + lane * 4;
        *(ushort4*)(ohi + off) = hh.u;
        *(ushort4*)(olo + off) = ll.u;
    }
}

// ---------------- barrier-free register GEMM (dense, unchanged) --------

__global__ __launch_bounds__(256, 4) void gemm_reg(
        const f16* __restrict__ Ahi, const f16* __restrict__ Alo,
        const f16* __restrict__ Wth, const f16* __restrict__ Wtl,
        const float* __restrict__ bias,
        float* __restrict__ Of32, f16* __restrict__ Ohi, f16* __restrict__ Olo,
        int M, int relu) {
    int tid = threadIdx.x, w = tid >> 6, lane = tid & 63;
    int row0 = blockIdx.x * 32;
    int m = lane & 31, kh = lane >> 5;

    int ar = row0 + m; if (ar >= M) ar = M - 1;
    const f16* pAh = Ahi + (size_t)ar * 256 + kh * 8;
    const f16* pAl = Alo + (size_t)ar * 256 + kh * 8;
    const f16* pBh[2]; const f16* pBl[2];
    #pragma unroll
    for (int t = 0; t < 2; ++t) {
        int nn = w * 64 + t * 32 + m;
        pBh[t] = Wth + (size_t)nn * 256 + kh * 8;
        pBl[t] = Wtl + (size_t)nn * 256 + kh * 8;
    }

    f32x16 acc[2] = {};
    #pragma unroll 4
    for (int k8 = 0; k8 < 16; ++k8) {
        f16x8 ah = *(const f16x8*)(pAh + k8 * 16);
        f16x8 al = *(const f16x8*)(pAl + k8 * 16);
        #pragma unroll
        for (int t = 0; t < 2; ++t) {
            f16x8 bh = *(const f16x8*)(pBh[t] + k8 * 16);
            f16x8 bl = *(const f16x8*)(pBl[t] + k8 * 16);
            acc[t] = MFMA(ah, bh, acc[t]);
            acc[t] = MFMA(ah, bl, acc[t]);
            acc[t] = MFMA(al, bh, acc[t]);
        }
    }

    #pragma unroll
    for (int t = 0; t < 2; ++t) {
        int col = w * 64 + t * 32 + m;
        float bv = bias[col];
        #pragma unroll
        for (int r = 0; r < 16; ++r) {
            int row = row0 + (r & 3) + 8 * (r >> 2) + 4 * kh;
            if (row < M) {
                float v = acc[t][r] + bv;
                if (relu) v = fmaxf(v, 0.f);
                size_t idx = (size_t)row * 256 + col;
                if (Of32) Of32[idx] = v;
                if (Ohi) {
                    f16 h = (f16)v;
                    Ohi[idx] = h; Olo[idx] = (f16)(v - (float)h);
                }
            }
        }
    }
}

// ---------------- ctx GEMM: coalesced gather + B-register pipeline ------
// 64 rows x 256 cols, 4 waves, triple-buffered LDS stage (2-iter cover) and
// double-buffered B registers (1-iter cover). Per-iter FIFO per wave:
//   [LOADB(t+1) 16][STAGE(t+2) 4][MFMA(t): auto-wait vmcnt(24), satisfied]
//   [vmcnt(20) -> stage(t+1) done][s_barrier]
// B-load L2 latency leaves the critical path; only stage-HBM residual remains.

__global__ __launch_bounds__(256, 3) void ctx_gemm(
        const f16* __restrict__ fhi, const f16* __restrict__ flo,
        const int* __restrict__ perm, const int* __restrict__ plen,
        const int* __restrict__ label,
        const f16* __restrict__ Rth, const f16* __restrict__ Rtl,  // [256][2048] n-major
        const float* __restrict__ rbias, float* __restrict__ out,
        const f16* __restrict__ zp, int M) {
    __shared__ __align__(16) f16 LA[3][2][4096];   // [buf][mat][row*64+slot*8] = 48KB
    __shared__ int s_lbl[8][64];
    __shared__ int s_perm[64];
    __shared__ int s_max;
    int tid = threadIdx.x, w = tid >> 6, lane = tid & 63;
    int row0 = (int)(gridDim.x - 1 - blockIdx.x) * 64;   // longest-context blocks first
    int m = lane & 31, kh = lane >> 5;

    if (tid == 0) s_max = 0;
    __syncthreads();
    if (tid < 64) {
        int r = row0 + tid;
        int p = (r < M) ? perm[r] : -1;
        s_perm[tid] = p;
        int len = (r < M) ? plen[r] : 0;
        atomicMax(&s_max, len);
        int4 l0 = make_int4(-1, -1, -1, -1), l1 = l0;
        if (p >= 0) {
            l0 = *(const int4*)(label + (size_t)p * 8);
            l1 = *(const int4*)(label + (size_t)p * 8 + 4);
        }
        s_lbl[0][tid] = (0 < len) ? l0.x : -1;
        s_lbl[1][tid] = (1 < len) ? l0.y : -1;
        s_lbl[2][tid] = (2 < len) ? l0.z : -1;
        s_lbl[3][tid] = (3 < len) ? l0.w : -1;
        s_lbl[4][tid] = (4 < len) ? l1.x : -1;
        s_lbl[5][tid] = (5 < len) ? l1.y : -1;
        s_lbl[6][tid] = (6 < len) ? l1.z : -1;
        s_lbl[7][tid] = (7 < len) ? l1.w : -1;
    }
    __syncthreads();
    int T = s_max * 4;   // slabs: (j, k0/64)

    f32x16 acc[2][2] = {};   // [row-tile i][col-tile jt]

    if (T > 0) {
        // coalesced+swizzled STAGE (verified R6): call o = 8 rows x 8 chunks,
        // lane l -> row rg*8+(l>>3), global chunk (l&7)^(l>>3), linear LDS dest.
        #define STAGE(t_, b_)                                                     \
        {                                                                         \
            int j_ = (t_) >> 2, k0e_ = ((t_) & 3) * 64;                           \
            int rl_ = lane >> 3;                                                  \
            int k8s_ = (lane & 7) ^ rl_;                                          \
            _Pragma("unroll")                                                     \
            for (int q = 0; q < 4; ++q) {                                         \
                int o_ = w * 4 + q;                                               \
                int mat_ = o_ >> 3, rg_ = o_ & 7;                                 \
                int lbl_ = s_lbl[j_][rg_ * 8 + rl_];                              \
                const f16* base_ = mat_ ? flo : fhi;                              \
                const f16* g_ = (lbl_ >= 0)                                       \
                    ? base_ + (size_t)lbl_ * 256 + k0e_ + k8s_ * 8 : zp;          \
                gload_lds16(g_, &LA[b_][mat_][rg_ * 512]);                        \
            }                                                                     \
        }
        // load B slab tt into named register arrays (16 x f16x8)
        #define LOADB(BH_, BL_, tt_)                                              \
        {                                                                         \
            int j_ = (tt_) >> 2, k0e_ = ((tt_) & 3) * 64;                         \
            _Pragma("unroll")                                                     \
            for (int jt = 0; jt < 2; ++jt) {                                      \
                int nn_ = w * 64 + jt * 32 + m;                                   \
                size_t bo_ = (size_t)nn_ * 2048 + j_ * 256 + k0e_ + kh * 8;       \
                const f16* ph_ = Rth + bo_;                                       \
                const f16* pl_ = Rtl + bo_;                                       \
                _Pragma("unroll")                                                 \
                for (int s = 0; s < 4; ++s) {                                     \
                    BH_[s][jt] = *(const f16x8*)(ph_ + s * 16);                   \
                    BL_[s][jt] = *(const f16x8*)(pl_ + s * 16);                   \
                }                                                                 \
            }                                                                     \
        }
        #define COMPUTE(BH_, BL_, b_)                                             \
        {                                                                         \
            _Pragma("unroll")                                                     \
            for (int s = 0; s < 4; ++s) {                                         \
                int k8_ = s * 2 + kh;                                             \
                int slot_ = (k8_ ^ (m & 7)) * 8;                                  \
                f16x8 ah[2], al[2];                                               \
                _Pragma("unroll")                                                 \
                for (int i = 0; i < 2; ++i) {                                     \
                    int ro_ = (i * 32 + m) * 64;                                  \
                    ah[i] = *(const f16x8*)&LA[b_][0][ro_ + slot_];               \
                    al[i] = *(const f16x8*)&LA[b_][1][ro_ + slot_];               \
                }                                                                 \
                _Pragma("unroll")                                                 \
                for (int jt = 0; jt < 2; ++jt) {                                  \
                    _Pragma("unroll")                                             \
                    for (int i = 0; i < 2; ++i) {                                 \
                        acc[i][jt] = MFMA(ah[i], BH_[s][jt], acc[i][jt]);         \
                        acc[i][jt] = MFMA(ah[i], BL_[s][jt], acc[i][jt]);         \
                        acc[i][jt] = MFMA(al[i], BH_[s][jt], acc[i][jt]);         \
                    }                                                             \
                }                                                                 \
            }                                                                     \
        }
        #define BODY(CURH_, CURL_, NXTH_, NXTL_, t_)                              \
        {                                                                         \
            if ((t_) + 1 < T) LOADB(NXTH_, NXTL_, (t_) + 1);                      \
            __builtin_amdgcn_sched_barrier(0);                                    \
            if ((t_) + 2 < T) STAGE((t_) + 2, ((t_) + 2) % 3);                    \
            __builtin_amdgcn_sched_barrier(0);                                    \
            COMPUTE(CURH_, CURL_, (t_) % 3);                                      \
            if ((t_) + 1 < T) {                                                   \
                if ((t_) + 2 < T) {                                               \
                    asm volatile("s_waitcnt vmcnt(20)" ::: "memory");             \
                } else {                                                          \
                    asm volatile("s_waitcnt vmcnt(16)" ::: "memory");             \
                }                                                                 \
                __builtin_amdgcn_s_barrier();                                     \
                __builtin_amdgcn_sched_barrier(0);                                \
            }                                                                     \
        }

        f16x8 Bh0[4][2], Bl0[4][2], Bh1[4][2], Bl1[4][2];

        STAGE(0, 0);
        if (T > 1) STAGE(1, 1);
        LOADB(Bh0, Bl0, 0);
        if (T > 1) {
            asm volatile("s_waitcnt vmcnt(20)" ::: "memory");   // stage(0) done
        } else {
            asm volatile("s_waitcnt vmcnt(16)" ::: "memory");
        }
        __builtin_amdgcn_s_barrier();
        __builtin_amdgcn_sched_barrier(0);

        int t = 0;
        while (t < T) {
            BODY(Bh0, Bl0, Bh1, Bl1, t);
            ++t;
            if (t >= T) break;
            BODY(Bh1, Bl1, Bh0, Bl0, t);
            ++t;
        }
        #undef BODY
        #undef COMPUTE
        #undef LOADB
        #undef STAGE
    }

    #pragma unroll
    for (int jt = 0; jt < 2; ++jt) {
        int col = w * 64 + jt * 32 + m;
        float rbv = rbias[col];
        #pragma unroll
        for (int i = 0; i < 2; ++i) {
            #pragma unroll
            for (int r = 0; r < 16; ++r) {
                int lr = i * 32 + (r & 3) + 8 * (r >> 2) + 4 * kh;
                int p = s_perm[lr];
                if (p >= 0) {
                    size_t idx = (size_t)p * 256 + col;
                    float f2 = (float)fhi[idx] + (float)flo[idx];
                    out[idx] = f2 * (acc[i][jt][r] + rbv);
                }
            }
        }
    }
}

// ---------------- launch ----------------

extern "C" void kernel_launch(void* const* d_in, const int* in_sizes, int n_in,
                              void* d_out, int out_size, void* d_ws, size_t ws_size,
                              hipStream_t stream) {
    const float* x    = (const float*)d_in[0];
    const int*   edge = (const int*)d_in[1];
    const int*   lbl  = (const int*)d_in[2];
    const int*   clen = (const int*)d_in[3];
    const float* gW   = (const float*)d_in[4];
    const float* gb   = (const float*)d_in[5];
    const float* rW   = (const float*)d_in[6];
    const float* rb   = (const float*)d_in[7];

    const int N = in_sizes[3];
    const int E = in_sizes[1] / 2;

    char* ws = (char*)d_ws;
    size_t off = 0;
    auto take = [&](size_t bytes) -> char* {
        char* p = ws + off;
        off = (off + bytes + 255) & ~(size_t)255;
        return p;
    };
    // small control block: bcnt[256] bbase[257] bfill[256] chist[16] chbase[16] chfill[16]
    int*   g_small  = (int*)take(1024 * sizeof(int));
    int*   g_bcnt   = g_small;
    int*   g_bbase  = g_small + 256;
    int*   g_bfill  = g_small + 520;
    int*   g_chist  = g_small + 776;
    int*   g_chbase = g_small + 792;
    int*   g_chfill = g_small + 808;
    int*   row_ptr = (int*)take((size_t)(N + 1) * sizeof(int));
    int*   ew      = (int*)take((size_t)E * sizeof(int));
    int*   perm    = (int*)take((size_t)N * sizeof(int));
    int*   plen    = (int*)take((size_t)N * sizeof(int));
    float* inv_s   = (float*)take((size_t)N * sizeof(float));
    f16*   zp      = (f16*)take(1024);
    f16*   Wth     = (f16*)take((size_t)256 * 256 * sizeof(f16));
    f16*   Wtl     = (f16*)take((size_t)256 * 256 * sizeof(f16));
    f16*   Rth     = (f16*)take((size_t)256 * 2048 * sizeof(f16));
    f16*   Rtl     = (f16*)take((size_t)256 * 2048 * sizeof(f16));
    f16*   Ahi     = (f16*)take((size_t)N * 256 * sizeof(f16));
    f16*   Alo     = (f16*)take((size_t)N * 256 * sizeof(f16));
    float* Y1      = (float*)take((size_t)N * 256 * sizeof(float));
    f16*   Fhi     = (f16*)take((size_t)N * 256 * sizeof(f16));
    f16*   Flo     = (f16*)take((size_t)N * 256 * sizeof(f16));
    int2*  binned  = (int2*)Y1;   // dead before Y1's first use (gemm1)

    hipMemsetAsync(g_small, 0, 1024 * sizeof(int), stream);
    hipMemsetAsync(zp, 0, 1024, stream);

    int NB   = (N + 255) >> 8;
    int GBIN = (E + CHUNK - 1) / CHUNK;
    int CHN  = (N + GBIN - 1) / GBIN;

    bin_count<<<GBIN, 256, 0, stream>>>(edge + E, clen, g_bcnt, g_chist, E, N, CHN);
    scan_small<<<1, 256, 0, stream>>>(g_bcnt, g_bbase, g_chist, g_chbase, NB, E);
    bin_scatter<<<GBIN, 256, 0, stream>>>(edge, edge + E, clen, g_bbase, g_bfill,
                                          g_chbase, g_chfill, binned, perm, plen,
                                          E, N, CHN);
    csr_build<<<NB, 256, 0, stream>>>(binned, g_bbase, row_ptr, inv_s, ew, E, N);
    pre_trans<<<144, 256, 0, stream>>>(gW, Wth, Wtl, rW, Rth, Rtl);

    int gB32 = (N + 31) / 32;
    int gB64 = (N + 63) / 64;
    agg_split<<<(N + 3) / 4, 512, 0, stream>>>(x, ew, row_ptr, inv_s, Ahi, Alo, N);
    gemm_reg<<<gB32, 256, 0, stream>>>(Ahi, Alo, Wth, Wtl, gb, Y1, nullptr, nullptr, N, 1);
    agg_split<<<(N + 3) / 4, 512, 0, stream>>>(Y1, ew, row_ptr, inv_s, Ahi, Alo, N);
    gemm_reg<<<gB32, 256, 0, stream>>>(Ahi, Alo, Wth, Wtl, gb, nullptr, Fhi, Flo, N, 0);
    ctx_gemm<<<gB64, 256, 0, stream>>>(Fhi, Flo, perm, plen, lbl, Rth, Rtl,
                                       rb, (float*)d_out, zp, N);
}

// Round 8
// 808.931 us; speedup vs baseline: 1.2619x; 1.2619x over previous
//
#include <hip/hip_runtime.h>

typedef _Float16 f16;
typedef _Float16 f16x8 __attribute__((ext_vector_type(8)));
typedef float f32x16 __attribute__((ext_vector_type(16)));

#define MFMA(a, b, c) __builtin_amdgcn_mfma_f32_32x32x16_f16(a, b, c, 0, 0, 0)

__device__ __forceinline__ void gload_lds16(const f16* g, f16* l) {
    __builtin_amdgcn_global_load_lds(
        (const __attribute__((address_space(1))) unsigned int*)g,
        (__attribute__((address_space(3))) unsigned int*)l, 16, 0, 0);
}

// ---------------- preprocessing: two-level counting sort ----------------
// bucket = dst >> 8 (256 nodes per bucket). Assumes N <= 65536 (here N=50000).

#define NBMAX 256
#define CHUNK 8192
#define CAP   8192

// Per-block LDS histograms -> one global atomic per (block,bucket).
__global__ __launch_bounds__(256) void bin_count(
        const int* __restrict__ dst, const int* __restrict__ clen,
        int* __restrict__ gbc, int* __restrict__ ghist, int E, int n, int chn) {
    __shared__ int bc[NBMAX];
    __shared__ int ch[9];
    int tid = threadIdx.x;
    bc[tid] = 0;
    if (tid < 9) ch[tid] = 0;
    __syncthreads();
    int e0 = blockIdx.x * CHUNK, e1 = min(e0 + CHUNK, E);
    for (int i = e0 + tid; i < e1; i += 256)
        atomicAdd(&bc[dst[i] >> 8], 1);
    int n0 = blockIdx.x * chn, n1 = min(n0 + chn, n);
    for (int i = n0 + tid; i < n1; i += 256) {
        int l = clen[i]; l = max(0, min(8, l));
        atomicAdd(&ch[l], 1);
    }
    __syncthreads();
    if (bc[tid]) atomicAdd(&gbc[tid], bc[tid]);
    if (tid < 9 && ch[tid]) atomicAdd(&ghist[tid], ch[tid]);
}

// Exclusive scan of 196 bucket counts + 9 clen bins. One tiny block.
__global__ __launch_bounds__(256) void scan_small(
        const int* __restrict__ gbc, int* __restrict__ gbase,
        const int* __restrict__ ghist, int* __restrict__ chbase, int nb, int E) {
    __shared__ int s[NBMAX];
    int tid = threadIdx.x;
    int v = (tid < nb) ? gbc[tid] : 0;
    s[tid] = v;
    __syncthreads();
    for (int off = 1; off < 256; off <<= 1) {
        int u = (tid >= off) ? s[tid - off] : 0;
        __syncthreads();
        s[tid] += u;
        __syncthreads();
    }
    if (tid <= nb) gbase[tid] = (tid < nb) ? s[tid] - v : E;
    if (tid == 0) {
        int run = 0;
        for (int i = 0; i < 9; ++i) { int c = ghist[i]; chbase[i] = run; run += c; }
    }
}

// Bucket-grouped scatter with per-block reservations (contiguous runs, no
// per-edge global atomics). Also builds perm/plen the same way.
__global__ __launch_bounds__(256) void bin_scatter(
        const int* __restrict__ src, const int* __restrict__ dst,
        const int* __restrict__ clen,
        const int* __restrict__ gbase, int* __restrict__ gfill,
        const int* __restrict__ chbase, int* __restrict__ chfill,
        int2* __restrict__ binned, int* __restrict__ perm, int* __restrict__ plen,
        int E, int n, int chn) {
    __shared__ int bc[NBMAX], bb[NBMAX];
    __shared__ int cc[9], cb[9];
    int tid = threadIdx.x;
    bc[tid] = 0;
    if (tid < 9) cc[tid] = 0;
    __syncthreads();
    int e0 = blockIdx.x * CHUNK, e1 = min(e0 + CHUNK, E);
    for (int i = e0 + tid; i < e1; i += 256)
        atomicAdd(&bc[dst[i] >> 8], 1);
    int n0 = blockIdx.x * chn, n1 = min(n0 + chn, n);
    for (int i = n0 + tid; i < n1; i += 256) {
        int l = clen[i]; l = max(0, min(8, l));
        atomicAdd(&cc[l], 1);
    }
    __syncthreads();
    {
        int c = bc[tid];
        bb[tid] = c ? gbase[tid] + atomicAdd(&gfill[tid], c) : 0;
        bc[tid] = 0;
    }
    if (tid < 9) {
        int c = cc[tid];
        cb[tid] = c ? chbase[tid] + atomicAdd(&chfill[tid], c) : 0;
        cc[tid] = 0;
    }
    __syncthreads();
    for (int i = e0 + tid; i < e1; i += 256) {
        int d = dst[i], b = d >> 8;
        int p = bb[b] + atomicAdd(&bc[b], 1);
        binned[p] = make_int2(src[i], d);
    }
    for (int i = n0 + tid; i < n1; i += 256) {
        int l = clen[i]; l = max(0, min(8, l));
        int p = cb[l] + atomicAdd(&cc[l], 1);
        perm[p] = i;
        plen[p] = l;
    }
}

// One block per bucket: per-node counts+scan in LDS -> row_ptr/inv_s; scatter
// edges inside LDS, stream out coalesced.
__global__ __launch_bounds__(256) void csr_build(
        const int2* __restrict__ binned, const int* __restrict__ gbase,
        int* __restrict__ row_ptr, float* __restrict__ inv_s,
        int* __restrict__ ew, int E, int n) {
    __shared__ int cnt[256], base[256], fill[256];
    __shared__ int ebuf[CAP];
    int tid = threadIdx.x, b = blockIdx.x;
    int e0 = gbase[b], e1 = gbase[b + 1], sz = e1 - e0;
    cnt[tid] = 0;
    __syncthreads();
    for (int i = e0 + tid; i < e1; i += 256)
        atomicAdd(&cnt[binned[i].y & 255], 1);
    __syncthreads();
    int v = cnt[tid];
    base[tid] = v;
    __syncthreads();
    for (int off = 1; off < 256; off <<= 1) {
        int u = (tid >= off) ? base[tid - off] : 0;
        __syncthreads();
        base[tid] += u;
        __syncthreads();
    }
    int ex = base[tid] - v;
    base[tid] = ex;
    fill[tid] = 0;
    int node = b * 256 + tid;
    if (node < n) {
        row_ptr[node] = e0 + ex;
        inv_s[node] = rsqrtf((float)(v + 1));
    }
    if (b == 0 && tid == 0) row_ptr[n] = E;
    __syncthreads();
    for (int i = e0 + tid; i < e1; i += 256) {
        int2 q = binned[i];
        int lo = q.y & 255;
        int p = base[lo] + atomicAdd(&fill[lo], 1);
        if (p < CAP) ebuf[p] = q.x; else ew[e0 + p] = q.x;
    }
    __syncthreads();
    int lim = min(sz, CAP);
    for (int p = tid; p < lim; p += 256) ew[e0 + p] = ebuf[p];
}

// LDS-tiled transpose-split: W[k][256] -> Wt[n][k] hi/lo, coalesced both sides.
// blocks 0..127: rW tiles; 128..143: gW tiles.
__global__ __launch_bounds__(256) void pre_trans(
        const float* __restrict__ gW, f16* __restrict__ Wth, f16* __restrict__ Wtl,
        const float* __restrict__ rW, f16* __restrict__ Rth, f16* __restrict__ Rtl) {
    int b = blockIdx.x;
    __shared__ f16 Th[64][68], Tl[64][68];
    const float* src; f16 *dh, *dl; int K, k0, n0;
    if (b < 128) { src = rW; dh = Rth; dl = Rtl; K = 2048; k0 = (b >> 2) * 64; n0 = (b & 3) * 64; }
    else { int bb = b - 128; src = gW; dh = Wth; dl = Wtl; K = 256; k0 = (bb >> 2) * 64; n0 = (bb & 3) * 64; }
    int c = threadIdx.x & 63, r0 = threadIdx.x >> 6;
    for (int rr = r0; rr < 64; rr += 4) {
        float v = src[(size_t)(k0 + rr) * 256 + n0 + c];
        f16 h = (f16)v;
        Th[rr][c] = h; Tl[rr][c] = (f16)(v - (float)h);
    }
    __syncthreads();
    int k = threadIdx.x & 63, nr0 = threadIdx.x >> 6;
    for (int nn = nr0; nn < 64; nn += 4) {
        size_t oidx = (size_t)(n0 + nn) * K + k0 + k;
        dh[oidx] = Th[k][nn];
        dl[oidx] = Tl[k][nn];
    }
}

// ---------------- aggregation: 2 waves per node, 8-deep, LDS combine --------

union H4 { f16 f[4]; ushort4 u; };

__global__ __launch_bounds__(512, 4) void agg_split(const float* __restrict__ X,
        const int* __restrict__ ew, const int* __restrict__ rp,
        const float* __restrict__ invs, f16* __restrict__ ohi, f16* __restrict__ olo, int n) {
    __shared__ float part[4][256];
    int w = threadIdx.x >> 6, lane = threadIdx.x & 63;
    int local = w >> 1, half = w & 1;
    int node = blockIdx.x * 4 + local;
    bool active = node < n;
    float4 acc = make_float4(0.f, 0.f, 0.f, 0.f);
    float si = 0.f;
    if (active) {
        si = invs[node];
        int e0 = rp[node], e1 = rp[node + 1];
        int mid = e0 + ((e1 - e0 + 1) >> 1);
        int lo = half ? mid : e0;
        int hi = half ? e1 : mid;
        if (!half) {
            float4 a = *((const float4*)(X + (size_t)node * 256) + lane);
            acc = make_float4(a.x * si, a.y * si, a.z * si, a.w * si);
        }
        int e = lo;
        for (; e + 8 <= hi; e += 8) {
            int q[8]; float ws[8]; float4 v[8];
            #pragma unroll
            for (int u = 0; u < 8; ++u) q[u] = ew[e + u];
            #pragma unroll
            for (int u = 0; u < 8; ++u) ws[u] = invs[q[u]];
            #pragma unroll
            for (int u = 0; u < 8; ++u) v[u] = *((const float4*)(X + (size_t)q[u] * 256) + lane);
            #pragma unroll
            for (int u = 0; u < 8; ++u) {
                acc.x = fmaf(ws[u], v[u].x, acc.x); acc.y = fmaf(ws[u], v[u].y, acc.y);
                acc.z = fmaf(ws[u], v[u].z, acc.z); acc.w = fmaf(ws[u], v[u].w, acc.w);
            }
        }
        for (; e < hi; ++e) {
            int q = ew[e];
            float wq = invs[q];
            float4 v = *((const float4*)(X + (size_t)q * 256) + lane);
            acc.x = fmaf(wq, v.x, acc.x); acc.y = fmaf(wq, v.y, acc.y);
            acc.z = fmaf(wq, v.z, acc.z); acc.w = fmaf(wq, v.w, acc.w);
        }
    }
    if (half) *(float4*)&part[local][lane * 4] = acc;
    __syncthreads();
    if (!half && active) {
        float4 o = *(const float4*)&part[local][lane * 4];
        float v0 = si * (acc.x + o.x), v1 = si * (acc.y + o.y);
        float v2 = si * (acc.z + o.z), v3 = si * (acc.w + o.w);
        H4 hh, ll;
        f16 h;
        h = (f16)v0; hh.f[0] = h; ll.f[0] = (f16)(v0 - (float)h);
        h = (f16)v1; hh.f[1] = h; ll.f[1] = (f16)(v1 - (float)h);
        h = (f16)v2; hh.f[2] = h; ll.f[2] = (f16)(v2 - (float)h);
        h = (f16)v3; hh.f[3] = h; ll.f[3] = (f16)(v3 - (float)h);
        size_t off = (size_t)node * 256 + lane * 4;
        *(ushort4*)(ohi + off) = hh.u;
        *(ushort4*)(olo + off) = ll.u;
    }
}

// ---------------- barrier-free register GEMM (dense, unchanged) --------

__global__ __launch_bounds__(256, 4) void gemm_reg(
        const f16* __restrict__ Ahi, const f16* __restrict__ Alo,
        const f16* __restrict__ Wth, const f16* __restrict__ Wtl,
        const float* __restrict__ bias,
        float* __restrict__ Of32, f16* __restrict__ Ohi, f16* __restrict__ Olo,
        int M, int relu) {
    int tid = threadIdx.x, w = tid >> 6, lane = tid & 63;
    int row0 = blockIdx.x * 32;
    int m = lane & 31, kh = lane >> 5;

    int ar = row0 + m; if (ar >= M) ar = M - 1;
    const f16* pAh = Ahi + (size_t)ar * 256 + kh * 8;
    const f16* pAl = Alo + (size_t)ar * 256 + kh * 8;
    const f16* pBh[2]; const f16* pBl[2];
    #pragma unroll
    for (int t = 0; t < 2; ++t) {
        int nn = w * 64 + t * 32 + m;
        pBh[t] = Wth + (size_t)nn * 256 + kh * 8;
        pBl[t] = Wtl + (size_t)nn * 256 + kh * 8;
    }

    f32x16 acc[2] = {};
    #pragma unroll 4
    for (int k8 = 0; k8 < 16; ++k8) {
        f16x8 ah = *(const f16x8*)(pAh + k8 * 16);
        f16x8 al = *(const f16x8*)(pAl + k8 * 16);
        #pragma unroll
        for (int t = 0; t < 2; ++t) {
            f16x8 bh = *(const f16x8*)(pBh[t] + k8 * 16);
            f16x8 bl = *(const f16x8*)(pBl[t] + k8 * 16);
            acc[t] = MFMA(ah, bh, acc[t]);
            acc[t] = MFMA(ah, bl, acc[t]);
            acc[t] = MFMA(al, bh, acc[t]);
        }
    }

    #pragma unroll
    for (int t = 0; t < 2; ++t) {
        int col = w * 64 + t * 32 + m;
        float bv = bias[col];
        #pragma unroll
        for (int r = 0; r < 16; ++r) {
            int row = row0 + (r & 3) + 8 * (r >> 2) + 4 * kh;
            if (row < M) {
                float v = acc[t][r] + bv;
                if (relu) v = fmaxf(v, 0.f);
                size_t idx = (size_t)row * 256 + col;
                if (Of32) Of32[idx] = v;
                if (Ohi) {
                    f16 h = (f16)v;
                    Ohi[idx] = h; Olo[idx] = (f16)(v - (float)h);
                }
            }
        }
    }
}

// ---------------- ctx GEMM: 32-row blocks (2 dispatch rounds) + coalesced ------
// Block: 32 rows x 256 cols, 256 threads (4 waves). Grid ~1563 blocks = 2.03
// rounds of the 768 resident slots -> short-context (round 2) blocks backfill
// as long blocks grind; kernel time ~ total-work/slots, not max-block.
// Slab = 32 rows x 64 k x 2 mats = 8KB, double-buffered (16KB).
// STAGE quad-coalesced (R6-verified): call = 8 rows x 8 chunks, lane l ->
// row rg*8+(l>>3), global chunk (l&7)^(l>>3), linear LDS dest; read addr
// r*64 + ((k8^(r&7))*8) -> 4-way bank conflict floor, hidden under MFMA.

__global__ __launch_bounds__(256) void ctx_gemm(
        const f16* __restrict__ fhi, const f16* __restrict__ flo,
        const int* __restrict__ perm, const int* __restrict__ plen,
        const int* __restrict__ label,
        const f16* __restrict__ Rth, const f16* __restrict__ Rtl,  // [256][2048] n-major
        const float* __restrict__ rbias, float* __restrict__ out,
        const f16* __restrict__ zp, int M) {
    __shared__ __align__(16) f16 LA[2][2][2048];   // [buf][mat][row*64+slot*8] = 16KB
    __shared__ int s_lbl[8][32];
    __shared__ int s_perm[32];
    __shared__ int s_max;
    int tid = threadIdx.x, w = tid >> 6, lane = tid & 63;
    int row0 = (int)(gridDim.x - 1 - blockIdx.x) * 32;   // longest-context blocks first
    int m = lane & 31, kh = lane >> 5;

    if (tid == 0) s_max = 0;
    __syncthreads();
    if (tid < 32) {
        int r = row0 + tid;
        int p = (r < M) ? perm[r] : -1;
        s_perm[tid] = p;
        int len = (r < M) ? plen[r] : 0;
        atomicMax(&s_max, len);
        int4 l0 = make_int4(-1, -1, -1, -1), l1 = l0;
        if (p >= 0) {
            l0 = *(const int4*)(label + (size_t)p * 8);
            l1 = *(const int4*)(label + (size_t)p * 8 + 4);
        }
        s_lbl[0][tid] = (0 < len) ? l0.x : -1;
        s_lbl[1][tid] = (1 < len) ? l0.y : -1;
        s_lbl[2][tid] = (2 < len) ? l0.z : -1;
        s_lbl[3][tid] = (3 < len) ? l0.w : -1;
        s_lbl[4][tid] = (4 < len) ? l1.x : -1;
        s_lbl[5][tid] = (5 < len) ? l1.y : -1;
        s_lbl[6][tid] = (6 < len) ? l1.z : -1;
        s_lbl[7][tid] = (7 < len) ? l1.w : -1;
    }
    __syncthreads();
    int T = s_max * 4;   // slabs: (j, k0/64)

    f32x16 acc[2] = {};   // [col-tile jt]

    if (T > 0) {
        // stage slab t into buf b: 8 calls total (2 per wave). Call o:
        // mat = o>>2, rg = o&3 (rows rg*8..+7). Lane l: row rg*8+(l>>3),
        // global chunk (l&7)^(l>>3), LDS dest elem rg*512 + l*8 (linear).
        #define STAGE(t_, b_)                                                     \
        {                                                                         \
            int j_ = (t_) >> 2, k0e_ = ((t_) & 3) * 64;                           \
            int rl_ = lane >> 3;                                                  \
            int k8s_ = (lane & 7) ^ rl_;                                          \
            _Pragma("unroll")                                                     \
            for (int q = 0; q < 2; ++q) {                                         \
                int o_ = w * 2 + q;                                               \
                int mat_ = o_ >> 2, rg_ = o_ & 3;                                 \
                int lbl_ = s_lbl[j_][rg_ * 8 + rl_];                              \
                const f16* base_ = mat_ ? flo : fhi;                              \
                const f16* g_ = (lbl_ >= 0)                                       \
                    ? base_ + (size_t)lbl_ * 256 + k0e_ + k8s_ * 8 : zp;          \
                gload_lds16(g_, &LA[b_][mat_][rg_ * 512]);                        \
            }                                                                     \
        }
        STAGE(0, 0);
        __syncthreads();
        for (int t = 0; t < T; ++t) {
            if (t + 1 < T) STAGE(t + 1, (t + 1) & 1);
            int b = t & 1;
            int j = t >> 2, k0e = (t & 3) * 64;
            const f16* pBh[2]; const f16* pBl[2];
            #pragma unroll
            for (int jt = 0; jt < 2; ++jt) {
                int nn = w * 64 + jt * 32 + m;
                size_t boff = (size_t)nn * 2048 + j * 256 + k0e + kh * 8;
                pBh[jt] = Rth + boff;
                pBl[jt] = Rtl + boff;
            }
            #pragma unroll
            for (int s = 0; s < 4; ++s) {
                int k8 = s * 2 + kh;
                int slot = (k8 ^ (m & 7)) * 8;
                f16x8 ah = *(const f16x8*)&LA[b][0][m * 64 + slot];
                f16x8 al = *(const f16x8*)&LA[b][1][m * 64 + slot];
                #pragma unroll
                for (int jt = 0; jt < 2; ++jt) {
                    f16x8 bh = *(const f16x8*)(pBh[jt] + s * 16);
                    f16x8 bl = *(const f16x8*)(pBl[jt] + s * 16);
                    acc[jt] = MFMA(ah, bh, acc[jt]);
                    acc[jt] = MFMA(ah, bl, acc[jt]);
                    acc[jt] = MFMA(al, bh, acc[jt]);
                }
            }
            __syncthreads();
        }
        #undef STAGE
    }

    #pragma unroll
    for (int jt = 0; jt < 2; ++jt) {
        int col = w * 64 + jt * 32 + m;
        float rbv = rbias[col];
        #pragma unroll
        for (int r = 0; r < 16; ++r) {
            int lr = (r & 3) + 8 * (r >> 2) + 4 * kh;
            int p = s_perm[lr];
            if (p >= 0) {
                size_t idx = (size_t)p * 256 + col;
                float f2 = (float)fhi[idx] + (float)flo[idx];
                out[idx] = f2 * (acc[jt][r] + rbv);
            }
        }
    }
}

// ---------------- launch ----------------

extern "C" void kernel_launch(void* const* d_in, const int* in_sizes, int n_in,
                              void* d_out, int out_size, void* d_ws, size_t ws_size,
                              hipStream_t stream) {
    const float* x    = (const float*)d_in[0];
    const int*   edge = (const int*)d_in[1];
    const int*   lbl  = (const int*)d_in[2];
    const int*   clen = (const int*)d_in[3];
    const float* gW   = (const float*)d_in[4];
    const float* gb   = (const float*)d_in[5];
    const float* rW   = (const float*)d_in[6];
    const float* rb   = (const float*)d_in[7];

    const int N = in_sizes[3];
    const int E = in_sizes[1] / 2;

    char* ws = (char*)d_ws;
    size_t off = 0;
    auto take = [&](size_t bytes) -> char* {
        char* p = ws + off;
        off = (off + bytes + 255) & ~(size_t)255;
        return p;
    };
    // small control block: bcnt[256] bbase[257] bfill[256] chist[16] chbase[16] chfill[16]
    int*   g_small  = (int*)take(1024 * sizeof(int));
    int*   g_bcnt   = g_small;
    int*   g_bbase  = g_small + 256;
    int*   g_bfill  = g_small + 520;
    int*   g_chist  = g_small + 776;
    int*   g_chbase = g_small + 792;
    int*   g_chfill = g_small + 808;
    int*   row_ptr = (int*)take((size_t)(N + 1) * sizeof(int));
    int*   ew      = (int*)take((size_t)E * sizeof(int));
    int*   perm    = (int*)take((size_t)N * sizeof(int));
    int*   plen    = (int*)take((size_t)N * sizeof(int));
    float* inv_s   = (float*)take((size_t)N * sizeof(float));
    f16*   zp      = (f16*)take(1024);
    f16*   Wth     = (f16*)take((size_t)256 * 256 * sizeof(f16));
    f16*   Wtl     = (f16*)take((size_t)256 * 256 * sizeof(f16));
    f16*   Rth     = (f16*)take((size_t)256 * 2048 * sizeof(f16));
    f16*   Rtl     = (f16*)take((size_t)256 * 2048 * sizeof(f16));
    f16*   Ahi     = (f16*)take((size_t)N * 256 * sizeof(f16));
    f16*   Alo     = (f16*)take((size_t)N * 256 * sizeof(f16));
    float* Y1      = (float*)take((size_t)N * 256 * sizeof(float));
    f16*   Fhi     = (f16*)take((size_t)N * 256 * sizeof(f16));
    f16*   Flo     = (f16*)take((size_t)N * 256 * sizeof(f16));
    int2*  binned  = (int2*)Y1;   // dead before Y1's first use (gemm1)

    hipMemsetAsync(g_small, 0, 1024 * sizeof(int), stream);
    hipMemsetAsync(zp, 0, 1024, stream);

    int NB   = (N + 255) >> 8;
    int GBIN = (E + CHUNK - 1) / CHUNK;
    int CHN  = (N + GBIN - 1) / GBIN;

    bin_count<<<GBIN, 256, 0, stream>>>(edge + E, clen, g_bcnt, g_chist, E, N, CHN);
    scan_small<<<1, 256, 0, stream>>>(g_bcnt, g_bbase, g_chist, g_chbase, NB, E);
    bin_scatter<<<GBIN, 256, 0, stream>>>(edge, edge + E, clen, g_bbase, g_bfill,
                                          g_chbase, g_chfill, binned, perm, plen,
                                          E, N, CHN);
    csr_build<<<NB, 256, 0, stream>>>(binned, g_bbase, row_ptr, inv_s, ew, E, N);
    pre_trans<<<144, 256, 0, stream>>>(gW, Wth, Wtl, rW, Rth, Rtl);

    int gB32 = (N + 31) / 32;
    agg_split<<<(N + 3) / 4, 512, 0, stream>>>(x, ew, row_ptr, inv_s, Ahi, Alo, N);
    gemm_reg<<<gB32, 256, 0, stream>>>(Ahi, Alo, Wth, Wtl, gb, Y1, nullptr, nullptr, N, 1);
    agg_split<<<(N + 3) / 4, 512, 0, stream>>>(Y1, ew, row_ptr, inv_s, Ahi, Alo, N);
    gemm_reg<<<gB32, 256, 0, stream>>>(Ahi, Alo, Wth, Wtl, gb, nullptr, Fhi, Flo, N, 0);
    ctx_gemm<<<gB32, 256, 0, stream>>>(Fhi, Flo, perm, plen, lbl, Rth, Rtl,
                                       rb, (float*)d_out, zp, N);
}

// Round 9
// 670.719 us; speedup vs baseline: 1.5219x; 1.2061x over previous
//
#include <hip/hip_runtime.h>

typedef _Float16 f16;
typedef _Float16 f16x8 __attribute__((ext_vector_type(8)));
typedef float f32x16 __attribute__((ext_vector_type(16)));

#define MFMA(a, b, c) __builtin_amdgcn_mfma_f32_32x32x16_f16(a, b, c, 0, 0, 0)

__device__ __forceinline__ void gload_lds16(const f16* g, f16* l) {
    __builtin_amdgcn_global_load_lds(
        (const __attribute__((address_space(1))) unsigned int*)g,
        (__attribute__((address_space(3))) unsigned int*)l, 16, 0, 0);
}

// ---------------- preprocessing: two-level counting sort ----------------
// bucket = dst >> 8 (256 nodes per bucket). Assumes N <= 65536 (here N=50000).

#define NBMAX 256
#define CHUNK 8192
#define CAP   8192

// Fused: blocks 0..nbc-1 do per-block LDS histograms; blocks nbc.. do the
// weight transpose-split (independent work, saves a launch).
__global__ __launch_bounds__(256) void bin_count_trans(
        const int* __restrict__ dst, const int* __restrict__ clen,
        int* __restrict__ gbc, int* __restrict__ ghist, int E, int n, int chn,
        int nbc,
        const float* __restrict__ gW, f16* __restrict__ Wth, f16* __restrict__ Wtl,
        const float* __restrict__ rW, f16* __restrict__ Rth, f16* __restrict__ Rtl) {
    __shared__ int bc[NBMAX];
    __shared__ int ch[9];
    __shared__ f16 Th[64][68], Tl[64][68];
    int tid = threadIdx.x;
    if ((int)blockIdx.x >= nbc) {
        int b = (int)blockIdx.x - nbc;
        const float* src; f16 *dh, *dl; int K, k0, n0;
        if (b < 128) { src = rW; dh = Rth; dl = Rtl; K = 2048; k0 = (b >> 2) * 64; n0 = (b & 3) * 64; }
        else { int bb = b - 128; src = gW; dh = Wth; dl = Wtl; K = 256; k0 = (bb >> 2) * 64; n0 = (bb & 3) * 64; }
        int c = tid & 63, r0 = tid >> 6;
        for (int rr = r0; rr < 64; rr += 4) {
            float v = src[(size_t)(k0 + rr) * 256 + n0 + c];
            f16 h = (f16)v;
            Th[rr][c] = h; Tl[rr][c] = (f16)(v - (float)h);
        }
        __syncthreads();
        int k = tid & 63, nr0 = tid >> 6;
        for (int nn = nr0; nn < 64; nn += 4) {
            size_t oidx = (size_t)(n0 + nn) * K + k0 + k;
            dh[oidx] = Th[k][nn];
            dl[oidx] = Tl[k][nn];
        }
        return;
    }
    bc[tid] = 0;
    if (tid < 9) ch[tid] = 0;
    __syncthreads();
    int e0 = blockIdx.x * CHUNK, e1 = min(e0 + CHUNK, E);
    for (int i = e0 + tid; i < e1; i += 256)
        atomicAdd(&bc[dst[i] >> 8], 1);
    int n0 = blockIdx.x * chn, n1 = min(n0 + chn, n);
    for (int i = n0 + tid; i < n1; i += 256) {
        int l = clen[i]; l = max(0, min(8, l));
        atomicAdd(&ch[l], 1);
    }
    __syncthreads();
    if (bc[tid]) atomicAdd(&gbc[tid], bc[tid]);
    if (tid < 9 && ch[tid]) atomicAdd(&ghist[tid], ch[tid]);
}

// Exclusive scan of bucket counts + 9 clen bins. One tiny block.
__global__ __launch_bounds__(256) void scan_small(
        const int* __restrict__ gbc, int* __restrict__ gbase,
        const int* __restrict__ ghist, int* __restrict__ chbase, int nb, int E) {
    __shared__ int s[NBMAX];
    int tid = threadIdx.x;
    int v = (tid < nb) ? gbc[tid] : 0;
    s[tid] = v;
    __syncthreads();
    for (int off = 1; off < 256; off <<= 1) {
        int u = (tid >= off) ? s[tid - off] : 0;
        __syncthreads();
        s[tid] += u;
        __syncthreads();
    }
    if (tid <= nb) gbase[tid] = (tid < nb) ? s[tid] - v : E;
    if (tid == 0) {
        int run = 0;
        for (int i = 0; i < 9; ++i) { int c = ghist[i]; chbase[i] = run; run += c; }
    }
}

// Bucket-grouped scatter with per-block reservations (contiguous runs, no
// per-edge global atomics). Also builds perm/plen the same way.
__global__ __launch_bounds__(256) void bin_scatter(
        const int* __restrict__ src, const int* __restrict__ dst,
        const int* __restrict__ clen,
        const int* __restrict__ gbase, int* __restrict__ gfill,
        const int* __restrict__ chbase, int* __restrict__ chfill,
        int2* __restrict__ binned, int* __restrict__ perm, int* __restrict__ plen,
        int E, int n, int chn) {
    __shared__ int bc[NBMAX], bb[NBMAX];
    __shared__ int cc[9], cb[9];
    int tid = threadIdx.x;
    bc[tid] = 0;
    if (tid < 9) cc[tid] = 0;
    __syncthreads();
    int e0 = blockIdx.x * CHUNK, e1 = min(e0 + CHUNK, E);
    for (int i = e0 + tid; i < e1; i += 256)
        atomicAdd(&bc[dst[i] >> 8], 1);
    int n0 = blockIdx.x * chn, n1 = min(n0 + chn, n);
    for (int i = n0 + tid; i < n1; i += 256) {
        int l = clen[i]; l = max(0, min(8, l));
        atomicAdd(&cc[l], 1);
    }
    __syncthreads();
    {
        int c = bc[tid];
        bb[tid] = c ? gbase[tid] + atomicAdd(&gfill[tid], c) : 0;
        bc[tid] = 0;
    }
    if (tid < 9) {
        int c = cc[tid];
        cb[tid] = c ? chbase[tid] + atomicAdd(&chfill[tid], c) : 0;
        cc[tid] = 0;
    }
    __syncthreads();
    for (int i = e0 + tid; i < e1; i += 256) {
        int d = dst[i], b = d >> 8;
        int p = bb[b] + atomicAdd(&bc[b], 1);
        binned[p] = make_int2(src[i], d);
    }
    for (int i = n0 + tid; i < n1; i += 256) {
        int l = clen[i]; l = max(0, min(8, l));
        int p = cb[l] + atomicAdd(&cc[l], 1);
        perm[p] = i;
        plen[p] = l;
    }
}

// One block per bucket: per-node counts+scan in LDS -> row_ptr/inv_s; scatter
// edges inside LDS, stream out coalesced.
__global__ __launch_bounds__(256) void csr_build(
        const int2* __restrict__ binned, const int* __restrict__ gbase,
        int* __restrict__ row_ptr, float* __restrict__ inv_s,
        int* __restrict__ ew, int E, int n) {
    __shared__ int cnt[256], base[256], fill[256];
    __shared__ int ebuf[CAP];
    int tid = threadIdx.x, b = blockIdx.x;
    int e0 = gbase[b], e1 = gbase[b + 1], sz = e1 - e0;
    cnt[tid] = 0;
    __syncthreads();
    for (int i = e0 + tid; i < e1; i += 256)
        atomicAdd(&cnt[binned[i].y & 255], 1);
    __syncthreads();
    int v = cnt[tid];
    base[tid] = v;
    __syncthreads();
    for (int off = 1; off < 256; off <<= 1) {
        int u = (tid >= off) ? base[tid - off] : 0;
        __syncthreads();
        base[tid] += u;
        __syncthreads();
    }
    int ex = base[tid] - v;
    base[tid] = ex;
    fill[tid] = 0;
    int node = b * 256 + tid;
    if (node < n) {
        row_ptr[node] = e0 + ex;
        inv_s[node] = rsqrtf((float)(v + 1));
    }
    if (b == 0 && tid == 0) row_ptr[n] = E;
    __syncthreads();
    for (int i = e0 + tid; i < e1; i += 256) {
        int2 q = binned[i];
        int lo = q.y & 255;
        int p = base[lo] + atomicAdd(&fill[lo], 1);
        if (p < CAP) ebuf[p] = q.x; else ew[e0 + p] = q.x;
    }
    __syncthreads();
    int lim = min(sz, CAP);
    for (int p = tid; p < lim; p += 256) ew[e0 + p] = ebuf[p];
}

// ---------------- aggregation: 2 waves per node, 8-deep, LDS combine --------

union H4 { f16 f[4]; ushort4 u; };

__global__ __launch_bounds__(512, 4) void agg_split(const float* __restrict__ X,
        const int* __restrict__ ew, const int* __restrict__ rp,
        const float* __restrict__ invs, f16* __restrict__ ohi, f16* __restrict__ olo, int n) {
    __shared__ float part[4][256];
    int w = threadIdx.x >> 6, lane = threadIdx.x & 63;
    int local = w >> 1, half = w & 1;
    int node = blockIdx.x * 4 + local;
    bool active = node < n;
    float4 acc = make_float4(0.f, 0.f, 0.f, 0.f);
    float si = 0.f;
    if (active) {
        si = invs[node];
        int e0 = rp[node], e1 = rp[node + 1];
        int mid = e0 + ((e1 - e0 + 1) >> 1);
        int lo = half ? mid : e0;
        int hi = half ? e1 : mid;
        if (!half) {
            float4 a = *((const float4*)(X + (size_t)node * 256) + lane);
            acc = make_float4(a.x * si, a.y * si, a.z * si, a.w * si);
        }
        int e = lo;
        for (; e + 8 <= hi; e += 8) {
            int q[8]; float ws[8]; float4 v[8];
            #pragma unroll
            for (int u = 0; u < 8; ++u) q[u] = ew[e + u];
            #pragma unroll
            for (int u = 0; u < 8; ++u) ws[u] = invs[q[u]];
            #pragma unroll
            for (int u = 0; u < 8; ++u) v[u] = *((const float4*)(X + (size_t)q[u] * 256) + lane);
            #pragma unroll
            for (int u = 0; u < 8; ++u) {
                acc.x = fmaf(ws[u], v[u].x, acc.x); acc.y = fmaf(ws[u], v[u].y, acc.y);
                acc.z = fmaf(ws[u], v[u].z, acc.z); acc.w = fmaf(ws[u], v[u].w, acc.w);
            }
        }
        for (; e < hi; ++e) {
            int q = ew[e];
            float wq = invs[q];
            float4 v = *((const float4*)(X + (size_t)q * 256) + lane);
            acc.x = fmaf(wq, v.x, acc.x); acc.y = fmaf(wq, v.y, acc.y);
            acc.z = fmaf(wq, v.z, acc.z); acc.w = fmaf(wq, v.w, acc.w);
        }
    }
    if (half) *(float4*)&part[local][lane * 4] = acc;
    __syncthreads();
    if (!half && active) {
        float4 o = *(const float4*)&part[local][lane * 4];
        float v0 = si * (acc.x + o.x), v1 = si * (acc.y + o.y);
        float v2 = si * (acc.z + o.z), v3 = si * (acc.w + o.w);
        H4 hh, ll;
        f16 h;
        h = (f16)v0; hh.f[0] = h; ll.f[0] = (f16)(v0 - (float)h);
        h = (f16)v1; hh.f[1] = h; ll.f[1] = (f16)(v1 - (float)h);
        h = (f16)v2; hh.f[2] = h; ll.f[2] = (f16)(v2 - (float)h);
        h = (f16)v3; hh.f[3] = h; ll.f[3] = (f16)(v3 - (float)h);
        size_t off = (size_t)node * 256 + lane * 4;
        *(ushort4*)(ohi + off) = hh.u;
        *(ushort4*)(olo + off) = ll.u;
    }
}

// ---------------- dense GEMM on the R6 ctx skeleton: coalesced LDS staging ----
// 64 rows x 256 cols, 4 waves, triple-buffered counted-vmcnt loop (verified in
// R6's ctx_gemm). Rows are sequential (row0+..), so STAGE streams contiguous
// 128B row-chunks: 16 lines/call, fully coalesced — removes the old per-lane
// strided A-read (~32 lines/instr) that capped gemm_reg at ~2.5 TB/s.

__global__ __launch_bounds__(256, 3) void gemm_lds(
        const f16* __restrict__ Ahi, const f16* __restrict__ Alo,
        const f16* __restrict__ Wth, const f16* __restrict__ Wtl,  // [256][256] n-major
        const float* __restrict__ bias,
        float* __restrict__ Of32, f16* __restrict__ Ohi, f16* __restrict__ Olo,
        int M, int relu) {
    __shared__ __align__(16) f16 LA[3][2][4096];   // [buf][mat][row*64+slot*8] = 48KB
    int tid = threadIdx.x, w = tid >> 6, lane = tid & 63;
    int row0 = (int)blockIdx.x * 64;
    int m = lane & 31, kh = lane >> 5;
    const int T = 4;   // K=256 in 4 slabs of 64

    f32x16 acc[2][2] = {};   // [row-tile i][col-tile jt]

    {
        // STAGE slab t (k0e=t*64) into buf b: wave w does calls w*4..w*4+3 of 16.
        // call o: mat=o>>3, rg=o&7 (rows rg*8..+7). lane l: row rg*8+(l>>3),
        // chunk (l&7)^(l>>3) (XOR pre-swizzle), linear LDS dest rg*512+l*8.
        #define STAGE(t_, b_)                                                     \
        {                                                                         \
            int k0e_ = (t_) * 64;                                                 \
            int rl_ = lane >> 3;                                                  \
            int k8s_ = (lane & 7) ^ rl_;                                          \
            _Pragma("unroll")                                                     \
            for (int q = 0; q < 4; ++q) {                                         \
                int o_ = w * 4 + q;                                               \
                int mat_ = o_ >> 3, rg_ = o_ & 7;                                 \
                int r_ = row0 + rg_ * 8 + rl_;                                    \
                if (r_ >= M) r_ = M - 1;                                          \
                const f16* base_ = mat_ ? Alo : Ahi;                              \
                const f16* g_ = base_ + (size_t)r_ * 256 + k0e_ + k8s_ * 8;       \
                gload_lds16(g_, &LA[b_][mat_][rg_ * 512]);                        \
            }                                                                     \
        }
        STAGE(0, 0);
        STAGE(1, 1);
        asm volatile("s_waitcnt vmcnt(0)" ::: "memory");
        __builtin_amdgcn_s_barrier();
        __builtin_amdgcn_sched_barrier(0);
        for (int t = 0; t < T; ++t) {
            int b = t % 3;
            int k0e = t * 64;
            f16x8 Bh[4][2], Bl[4][2];
            #pragma unroll
            for (int jt = 0; jt < 2; ++jt) {
                int nn = w * 64 + jt * 32 + m;
                size_t boff = (size_t)nn * 256 + k0e + kh * 8;
                const f16* ph = Wth + boff;
                const f16* pl = Wtl + boff;
                #pragma unroll
                for (int s = 0; s < 4; ++s) {
                    Bh[s][jt] = *(const f16x8*)(ph + s * 16);
                    Bl[s][jt] = *(const f16x8*)(pl + s * 16);
                }
            }
            __builtin_amdgcn_sched_barrier(0);
            if (t + 2 < T) STAGE(t + 2, (t + 2) % 3);
            __builtin_amdgcn_sched_barrier(0);
            #pragma unroll
            for (int s = 0; s < 4; ++s) {
                int k8 = s * 2 + kh;
                int slot = (k8 ^ (m & 7)) * 8;
                f16x8 ah[2], al[2];
                #pragma unroll
                for (int i = 0; i < 2; ++i) {
                    int ro = (i * 32 + m) * 64;
                    ah[i] = *(const f16x8*)&LA[b][0][ro + slot];
                    al[i] = *(const f16x8*)&LA[b][1][ro + slot];
                }
                #pragma unroll
                for (int jt = 0; jt < 2; ++jt) {
                    #pragma unroll
                    for (int i = 0; i < 2; ++i) {
                        acc[i][jt] = MFMA(ah[i], Bh[s][jt], acc[i][jt]);
                        acc[i][jt] = MFMA(ah[i], Bl[s][jt], acc[i][jt]);
                        acc[i][jt] = MFMA(al[i], Bh[s][jt], acc[i][jt]);
                    }
                }
            }
            if (t + 2 < T) {
                asm volatile("s_waitcnt vmcnt(4)" ::: "memory");
            } else {
                asm volatile("s_waitcnt vmcnt(0)" ::: "memory");
            }
            __builtin_amdgcn_s_barrier();
            __builtin_amdgcn_sched_barrier(0);
        }
        #undef STAGE
    }

    #pragma unroll
    for (int jt = 0; jt < 2; ++jt) {
        int col = w * 64 + jt * 32 + m;
        float bv = bias[col];
        #pragma unroll
        for (int i = 0; i < 2; ++i) {
            #pragma unroll
            for (int r = 0; r < 16; ++r) {
                int row = row0 + i * 32 + (r & 3) + 8 * (r >> 2) + 4 * kh;
                if (row < M) {
                    float v = acc[i][jt][r] + bv;
                    if (relu) v = fmaxf(v, 0.f);
                    size_t idx = (size_t)row * 256 + col;
                    if (Of32) Of32[idx] = v;
                    if (Ohi) {
                        f16 h = (f16)v;
                        Ohi[idx] = h; Olo[idx] = (f16)(v - (float)h);
                    }
                }
            }
        }
    }
}

// ---------------- ctx GEMM: R6-verified (coalesced gather, 3-buf counted) ----

__global__ __launch_bounds__(256, 3) void ctx_gemm(
        const f16* __restrict__ fhi, const f16* __restrict__ flo,
        const int* __restrict__ perm, const int* __restrict__ plen,
        const int* __restrict__ label,
        const f16* __restrict__ Rth, const f16* __restrict__ Rtl,  // [256][2048] n-major
        const float* __restrict__ rbias, float* __restrict__ out,
        const f16* __restrict__ zp, int M) {
    __shared__ __align__(16) f16 LA[3][2][4096];   // [buf][mat][row*64+slot*8] = 48KB
    __shared__ int s_lbl[8][64];
    __shared__ int s_perm[64];
    __shared__ int s_max;
    int tid = threadIdx.x, w = tid >> 6, lane = tid & 63;
    int row0 = (int)(gridDim.x - 1 - blockIdx.x) * 64;   // longest-context blocks first
    int m = lane & 31, kh = lane >> 5;

    if (tid == 0) s_max = 0;
    __syncthreads();
    if (tid < 64) {
        int r = row0 + tid;
        int p = (r < M) ? perm[r] : -1;
        s_perm[tid] = p;
        int len = (r < M) ? plen[r] : 0;
        atomicMax(&s_max, len);
        int4 l0 = make_int4(-1, -1, -1, -1), l1 = l0;
        if (p >= 0) {
            l0 = *(const int4*)(label + (size_t)p * 8);
            l1 = *(const int4*)(label + (size_t)p * 8 + 4);
        }
        s_lbl[0][tid] = (0 < len) ? l0.x : -1;
        s_lbl[1][tid] = (1 < len) ? l0.y : -1;
        s_lbl[2][tid] = (2 < len) ? l0.z : -1;
        s_lbl[3][tid] = (3 < len) ? l0.w : -1;
        s_lbl[4][tid] = (4 < len) ? l1.x : -1;
        s_lbl[5][tid] = (5 < len) ? l1.y : -1;
        s_lbl[6][tid] = (6 < len) ? l1.z : -1;
        s_lbl[7][tid] = (7 < len) ? l1.w : -1;
    }
    __syncthreads();
    int T = s_max * 4;   // slabs: (j, k0/64)

    f32x16 acc[2][2] = {};   // [row-tile i][col-tile jt]

    if (T > 0) {
        #define STAGE(t_, b_)                                                     \
        {                                                                         \
            int j_ = (t_) >> 2, k0e_ = ((t_) & 3) * 64;                           \
            int rl_ = lane >> 3;                                                  \
            int k8s_ = (lane & 7) ^ rl_;                                          \
            _Pragma("unroll")                                                     \
            for (int q = 0; q < 4; ++q) {                                         \
                int o_ = w * 4 + q;                                               \
                int mat_ = o_ >> 3, rg_ = o_ & 7;                                 \
                int lbl_ = s_lbl[j_][rg_ * 8 + rl_];                              \
                const f16* base_ = mat_ ? flo : fhi;                              \
                const f16* g_ = (lbl_ >= 0)                                       \
                    ? base_ + (size_t)lbl_ * 256 + k0e_ + k8s_ * 8 : zp;          \
                gload_lds16(g_, &LA[b_][mat_][rg_ * 512]);                        \
            }                                                                     \
        }
        STAGE(0, 0);
        if (T > 1) STAGE(1, 1);
        asm volatile("s_waitcnt vmcnt(0)" ::: "memory");
        __builtin_amdgcn_s_barrier();
        __builtin_amdgcn_sched_barrier(0);
        for (int t = 0; t < T; ++t) {
            int b = t % 3;
            int j = t >> 2, k0e = (t & 3) * 64;
            f16x8 Bh[4][2], Bl[4][2];
            #pragma unroll
            for (int jt = 0; jt < 2; ++jt) {
                int nn = w * 64 + jt * 32 + m;
                size_t boff = (size_t)nn * 2048 + j * 256 + k0e + kh * 8;
                const f16* ph = Rth + boff;
                const f16* pl = Rtl + boff;
                #pragma unroll
                for (int s = 0; s < 4; ++s) {
                    Bh[s][jt] = *(const f16x8*)(ph + s * 16);
                    Bl[s][jt] = *(const f16x8*)(pl + s * 16);
                }
            }
            __builtin_amdgcn_sched_barrier(0);
            if (t + 2 < T) STAGE(t + 2, (t + 2) % 3);
            __builtin_amdgcn_sched_barrier(0);
            #pragma unroll
            for (int s = 0; s < 4; ++s) {
                int k8 = s * 2 + kh;
                int slot = (k8 ^ (m & 7)) * 8;
                f16x8 ah[2], al[2];
                #pragma unroll
                for (int i = 0; i < 2; ++i) {
                    int ro = (i * 32 + m) * 64;
                    ah[i] = *(const f16x8*)&LA[b][0][ro + slot];
                    al[i] = *(const f16x8*)&LA[b][1][ro + slot];
                }
                #pragma unroll
                for (int jt = 0; jt < 2; ++jt) {
                    #pragma unroll
                    for (int i = 0; i < 2; ++i) {
                        acc[i][jt] = MFMA(ah[i], Bh[s][jt], acc[i][jt]);
                        acc[i][jt] = MFMA(ah[i], Bl[s][jt], acc[i][jt]);
                        acc[i][jt] = MFMA(al[i], Bh[s][jt], acc[i][jt]);
                    }
                }
            }
            if (t + 2 < T) {
                asm volatile("s_waitcnt vmcnt(4)" ::: "memory");
            } else {
                asm volatile("s_waitcnt vmcnt(0)" ::: "memory");
            }
            __builtin_amdgcn_s_barrier();
            __builtin_amdgcn_sched_barrier(0);
        }
        #undef STAGE
    }

    #pragma unroll
    for (int jt = 0; jt < 2; ++jt) {
        int col = w * 64 + jt * 32 + m;
        float rbv = rbias[col];
        #pragma unroll
        for (int i = 0; i < 2; ++i) {
            #pragma unroll
            for (int r = 0; r < 16; ++r) {
                int lr = i * 32 + (r & 3) + 8 * (r >> 2) + 4 * kh;
                int p = s_perm[lr];
                if (p >= 0) {
                    size_t idx = (size_t)p * 256 + col;
                    float f2 = (float)fhi[idx] + (float)flo[idx];
                    out[idx] = f2 * (acc[i][jt][r] + rbv);
                }
            }
        }
    }
}

// ---------------- launch ----------------

extern "C" void kernel_launch(void* const* d_in, const int* in_sizes, int n_in,
                              void* d_out, int out_size, void* d_ws, size_t ws_size,
                              hipStream_t stream) {
    const float* x    = (const float*)d_in[0];
    const int*   edge = (const int*)d_in[1];
    const int*   lbl  = (const int*)d_in[2];
    const int*   clen = (const int*)d_in[3];
    const float* gW   = (const float*)d_in[4];
    const float* gb   = (const float*)d_in[5];
    const float* rW   = (const float*)d_in[6];
    const float* rb   = (const float*)d_in[7];

    const int N = in_sizes[3];
    const int E = in_sizes[1] / 2;

    char* ws = (char*)d_ws;
    size_t off = 0;
    auto take = [&](size_t bytes) -> char* {
        char* p = ws + off;
        off = (off + bytes + 255) & ~(size_t)255;
        return p;
    };
    // small control block: bcnt[256] bbase[257] bfill[256] chist[16] chbase[16] chfill[16]
    int*   g_small  = (int*)take(1024 * sizeof(int));
    int*   g_bcnt   = g_small;
    int*   g_bbase  = g_small + 256;
    int*   g_bfill  = g_small + 520;
    int*   g_chist  = g_small + 776;
    int*   g_chbase = g_small + 792;
    int*   g_chfill = g_small + 808;
    int*   row_ptr = (int*)take((size_t)(N + 1) * sizeof(int));
    int*   ew      = (int*)take((size_t)E * sizeof(int));
    int*   perm    = (int*)take((size_t)N * sizeof(int));
    int*   plen    = (int*)take((size_t)N * sizeof(int));
    float* inv_s   = (float*)take((size_t)N * sizeof(float));
    f16*   zp      = (f16*)take(1024);
    f16*   Wth     = (f16*)take((size_t)256 * 256 * sizeof(f16));
    f16*   Wtl     = (f16*)take((size_t)256 * 256 * sizeof(f16));
    f16*   Rth     = (f16*)take((size_t)256 * 2048 * sizeof(f16));
    f16*   Rtl     = (f16*)take((size_t)256 * 2048 * sizeof(f16));
    f16*   Ahi     = (f16*)take((size_t)N * 256 * sizeof(f16));
    f16*   Alo     = (f16*)take((size_t)N * 256 * sizeof(f16));
    float* Y1      = (float*)take((size_t)N * 256 * sizeof(float));
    f16*   Fhi     = (f16*)take((size_t)N * 256 * sizeof(f16));
    f16*   Flo     = (f16*)take((size_t)N * 256 * sizeof(f16));
    int2*  binned  = (int2*)Y1;   // dead before Y1's first use (gemm1)

    hipMemsetAsync(g_small, 0, 1024 * sizeof(int), stream);
    hipMemsetAsync(zp, 0, 1024, stream);

    int NB   = (N + 255) >> 8;
    int GBIN = (E + CHUNK - 1) / CHUNK;
    int CHN  = (N + GBIN - 1) / GBIN;

    bin_count_trans<<<GBIN + 144, 256, 0, stream>>>(edge + E, clen, g_bcnt, g_chist,
                                                    E, N, CHN, GBIN,
                                                    gW, Wth, Wtl, rW, Rth, Rtl);
    scan_small<<<1, 256, 0, stream>>>(g_bcnt, g_bbase, g_chist, g_chbase, NB, E);
    bin_scatter<<<GBIN, 256, 0, stream>>>(edge, edge + E, clen, g_bbase, g_bfill,
                                          g_chbase, g_chfill, binned, perm, plen,
                                          E, N, CHN);
    csr_build<<<NB, 256, 0, stream>>>(binned, g_bbase, row_ptr, inv_s, ew, E, N);

    int gB64 = (N + 63) / 64;
    agg_split<<<(N + 3) / 4, 512, 0, stream>>>(x, ew, row_ptr, inv_s, Ahi, Alo, N);
    gemm_lds<<<gB64, 256, 0, stream>>>(Ahi, Alo, Wth, Wtl, gb, Y1, nullptr, nullptr, N, 1);
    agg_split<<<(N + 3) / 4, 512, 0, stream>>>(Y1, ew, row_ptr, inv_s, Ahi, Alo, N);
    gemm_lds<<<gB64, 256, 0, stream>>>(Ahi, Alo, Wth, Wtl, gb, nullptr, Fhi, Flo, N, 0);
    ctx_gemm<<<gB64, 256, 0, stream>>>(Fhi, Flo, perm, plen, lbl, Rth, Rtl,
                                       rb, (float*)d_out, zp, N);
}

// Round 10
// 669.271 us; speedup vs baseline: 1.5252x; 1.0022x over previous
//
#include <hip/hip_runtime.h>

typedef _Float16 f16;
typedef _Float16 f16x8 __attribute__((ext_vector_type(8)));
typedef float f32x16 __attribute__((ext_vector_type(16)));

#define MFMA(a, b, c) __builtin_amdgcn_mfma_f32_32x32x16_f16(a, b, c, 0, 0, 0)

__device__ __forceinline__ void gload_lds16(const f16* g, f16* l) {
    __builtin_amdgcn_global_load_lds(
        (const __attribute__((address_space(1))) unsigned int*)g,
        (__attribute__((address_space(3))) unsigned int*)l, 16, 0, 0);
}

// ---------------- preprocessing: two-level counting sort ----------------
// bucket = dst >> 8 (256 nodes per bucket). Assumes N <= 65536 (here N=50000).

#define NBMAX 256
#define CHUNK 8192
#define CAP   8192

// Fused: blocks 0..nbc-1 do per-block LDS histograms; blocks nbc.. do the
// weight transpose-split (independent work, saves a launch).
__global__ __launch_bounds__(256) void bin_count_trans(
        const int* __restrict__ dst, const int* __restrict__ clen,
        int* __restrict__ gbc, int* __restrict__ ghist, int E, int n, int chn,
        int nbc,
        const float* __restrict__ gW, f16* __restrict__ Wth, f16* __restrict__ Wtl,
        const float* __restrict__ rW, f16* __restrict__ Rth, f16* __restrict__ Rtl) {
    __shared__ int bc[NBMAX];
    __shared__ int ch[9];
    __shared__ f16 Th[64][68], Tl[64][68];
    int tid = threadIdx.x;
    if ((int)blockIdx.x >= nbc) {
        int b = (int)blockIdx.x - nbc;
        const float* src; f16 *dh, *dl; int K, k0, n0;
        if (b < 128) { src = rW; dh = Rth; dl = Rtl; K = 2048; k0 = (b >> 2) * 64; n0 = (b & 3) * 64; }
        else { int bb = b - 128; src = gW; dh = Wth; dl = Wtl; K = 256; k0 = (bb >> 2) * 64; n0 = (bb & 3) * 64; }
        int c = tid & 63, r0 = tid >> 6;
        for (int rr = r0; rr < 64; rr += 4) {
            float v = src[(size_t)(k0 + rr) * 256 + n0 + c];
            f16 h = (f16)v;
            Th[rr][c] = h; Tl[rr][c] = (f16)(v - (float)h);
        }
        __syncthreads();
        int k = tid & 63, nr0 = tid >> 6;
        for (int nn = nr0; nn < 64; nn += 4) {
            size_t oidx = (size_t)(n0 + nn) * K + k0 + k;
            dh[oidx] = Th[k][nn];
            dl[oidx] = Tl[k][nn];
        }
        return;
    }
    bc[tid] = 0;
    if (tid < 9) ch[tid] = 0;
    __syncthreads();
    int e0 = blockIdx.x * CHUNK, e1 = min(e0 + CHUNK, E);
    for (int i = e0 + tid; i < e1; i += 256)
        atomicAdd(&bc[dst[i] >> 8], 1);
    int n0 = blockIdx.x * chn, n1 = min(n0 + chn, n);
    for (int i = n0 + tid; i < n1; i += 256) {
        int l = clen[i]; l = max(0, min(8, l));
        atomicAdd(&ch[l], 1);
    }
    __syncthreads();
    if (bc[tid]) atomicAdd(&gbc[tid], bc[tid]);
    if (tid < 9 && ch[tid]) atomicAdd(&ghist[tid], ch[tid]);
}

// Exclusive scan of bucket counts + 9 clen bins. One tiny block.
__global__ __launch_bounds__(256) void scan_small(
        const int* __restrict__ gbc, int* __restrict__ gbase,
        const int* __restrict__ ghist, int* __restrict__ chbase, int nb, int E) {
    __shared__ int s[NBMAX];
    int tid = threadIdx.x;
    int v = (tid < nb) ? gbc[tid] : 0;
    s[tid] = v;
    __syncthreads();
    for (int off = 1; off < 256; off <<= 1) {
        int u = (tid >= off) ? s[tid - off] : 0;
        __syncthreads();
        s[tid] += u;
        __syncthreads();
    }
    if (tid <= nb) gbase[tid] = (tid < nb) ? s[tid] - v : E;
    if (tid == 0) {
        int run = 0;
        for (int i = 0; i < 9; ++i) { int c = ghist[i]; chbase[i] = run; run += c; }
    }
}

// Bucket-grouped scatter with per-block reservations (contiguous runs, no
// per-edge global atomics). Also builds perm/plen the same way.
__global__ __launch_bounds__(256) void bin_scatter(
        const int* __restrict__ src, const int* __restrict__ dst,
        const int* __restrict__ clen,
        const int* __restrict__ gbase, int* __restrict__ gfill,
        const int* __restrict__ chbase, int* __restrict__ chfill,
        int2* __restrict__ binned, int* __restrict__ perm, int* __restrict__ plen,
        int E, int n, int chn) {
    __shared__ int bc[NBMAX], bb[NBMAX];
    __shared__ int cc[9], cb[9];
    int tid = threadIdx.x;
    bc[tid] = 0;
    if (tid < 9) cc[tid] = 0;
    __syncthreads();
    int e0 = blockIdx.x * CHUNK, e1 = min(e0 + CHUNK, E);
    for (int i = e0 + tid; i < e1; i += 256)
        atomicAdd(&bc[dst[i] >> 8], 1);
    int n0 = blockIdx.x * chn, n1 = min(n0 + chn, n);
    for (int i = n0 + tid; i < n1; i += 256) {
        int l = clen[i]; l = max(0, min(8, l));
        atomicAdd(&cc[l], 1);
    }
    __syncthreads();
    {
        int c = bc[tid];
        bb[tid] = c ? gbase[tid] + atomicAdd(&gfill[tid], c) : 0;
        bc[tid] = 0;
    }
    if (tid < 9) {
        int c = cc[tid];
        cb[tid] = c ? chbase[tid] + atomicAdd(&chfill[tid], c) : 0;
        cc[tid] = 0;
    }
    __syncthreads();
    for (int i = e0 + tid; i < e1; i += 256) {
        int d = dst[i], b = d >> 8;
        int p = bb[b] + atomicAdd(&bc[b], 1);
        binned[p] = make_int2(src[i], d);
    }
    for (int i = n0 + tid; i < n1; i += 256) {
        int l = clen[i]; l = max(0, min(8, l));
        int p = cb[l] + atomicAdd(&cc[l], 1);
        perm[p] = i;
        plen[p] = l;
    }
}

// One block per bucket: per-node counts+scan in LDS -> row_ptr/inv_s; scatter
// edges inside LDS, stream out coalesced.
__global__ __launch_bounds__(256) void csr_build(
        const int2* __restrict__ binned, const int* __restrict__ gbase,
        int* __restrict__ row_ptr, float* __restrict__ inv_s,
        int* __restrict__ ew, int E, int n) {
    __shared__ int cnt[256], base[256], fill[256];
    __shared__ int ebuf[CAP];
    int tid = threadIdx.x, b = blockIdx.x;
    int e0 = gbase[b], e1 = gbase[b + 1], sz = e1 - e0;
    cnt[tid] = 0;
    __syncthreads();
    for (int i = e0 + tid; i < e1; i += 256)
        atomicAdd(&cnt[binned[i].y & 255], 1);
    __syncthreads();
    int v = cnt[tid];
    base[tid] = v;
    __syncthreads();
    for (int off = 1; off < 256; off <<= 1) {
        int u = (tid >= off) ? base[tid - off] : 0;
        __syncthreads();
        base[tid] += u;
        __syncthreads();
    }
    int ex = base[tid] - v;
    base[tid] = ex;
    fill[tid] = 0;
    int node = b * 256 + tid;
    if (node < n) {
        row_ptr[node] = e0 + ex;
        inv_s[node] = rsqrtf((float)(v + 1));
    }
    if (b == 0 && tid == 0) row_ptr[n] = E;
    __syncthreads();
    for (int i = e0 + tid; i < e1; i += 256) {
        int2 q = binned[i];
        int lo = q.y & 255;
        int p = base[lo] + atomicAdd(&fill[lo], 1);
        if (p < CAP) ebuf[p] = q.x; else ew[e0 + p] = q.x;
    }
    __syncthreads();
    int lim = min(sz, CAP);
    for (int p = tid; p < lim; p += 256) ew[e0 + p] = ebuf[p];
}

// ---------------- aggregation: 2 waves per node, 8-deep, LDS combine --------

union H4 { f16 f[4]; ushort4 u; };

__global__ __launch_bounds__(512, 4) void agg_split(const float* __restrict__ X,
        const int* __restrict__ ew, const int* __restrict__ rp,
        const float* __restrict__ invs, f16* __restrict__ ohi, f16* __restrict__ olo, int n) {
    __shared__ float part[4][256];
    int w = threadIdx.x >> 6, lane = threadIdx.x & 63;
    int local = w >> 1, half = w & 1;
    int node = blockIdx.x * 4 + local;
    bool active = node < n;
    float4 acc = make_float4(0.f, 0.f, 0.f, 0.f);
    float si = 0.f;
    if (active) {
        si = invs[node];
        int e0 = rp[node], e1 = rp[node + 1];
        int mid = e0 + ((e1 - e0 + 1) >> 1);
        int lo = half ? mid : e0;
        int hi = half ? e1 : mid;
        if (!half) {
            float4 a = *((const float4*)(X + (size_t)node * 256) + lane);
            acc = make_float4(a.x * si, a.y * si, a.z * si, a.w * si);
        }
        int e = lo;
        for (; e + 8 <= hi; e += 8) {
            int q[8]; float ws[8]; float4 v[8];
            #pragma unroll
            for (int u = 0; u < 8; ++u) q[u] = ew[e + u];
            #pragma unroll
            for (int u = 0; u < 8; ++u) ws[u] = invs[q[u]];
            #pragma unroll
            for (int u = 0; u < 8; ++u) v[u] = *((const float4*)(X + (size_t)q[u] * 256) + lane);
            #pragma unroll
            for (int u = 0; u < 8; ++u) {
                acc.x = fmaf(ws[u], v[u].x, acc.x); acc.y = fmaf(ws[u], v[u].y, acc.y);
                acc.z = fmaf(ws[u], v[u].z, acc.z); acc.w = fmaf(ws[u], v[u].w, acc.w);
            }
        }
        for (; e < hi; ++e) {
            int q = ew[e];
            float wq = invs[q];
            float4 v = *((const float4*)(X + (size_t)q * 256) + lane);
            acc.x = fmaf(wq, v.x, acc.x); acc.y = fmaf(wq, v.y, acc.y);
            acc.z = fmaf(wq, v.z, acc.z); acc.w = fmaf(wq, v.w, acc.w);
        }
    }
    if (half) *(float4*)&part[local][lane * 4] = acc;
    __syncthreads();
    if (!half && active) {
        float4 o = *(const float4*)&part[local][lane * 4];
        float v0 = si * (acc.x + o.x), v1 = si * (acc.y + o.y);
        float v2 = si * (acc.z + o.z), v3 = si * (acc.w + o.w);
        H4 hh, ll;
        f16 h;
        h = (f16)v0; hh.f[0] = h; ll.f[0] = (f16)(v0 - (float)h);
        h = (f16)v1; hh.f[1] = h; ll.f[1] = (f16)(v1 - (float)h);
        h = (f16)v2; hh.f[2] = h; ll.f[2] = (f16)(v2 - (float)h);
        h = (f16)v3; hh.f[3] = h; ll.f[3] = (f16)(v3 - (float)h);
        size_t off = (size_t)node * 256 + lane * 4;
        *(ushort4*)(ohi + off) = hh.u;
        *(ushort4*)(olo + off) = ll.u;
    }
}

// ---------------- dense GEMM on the R6 ctx skeleton (R9-verified) ----

__global__ __launch_bounds__(256, 3) void gemm_lds(
        const f16* __restrict__ Ahi, const f16* __restrict__ Alo,
        const f16* __restrict__ Wth, const f16* __restrict__ Wtl,  // [256][256] n-major
        const float* __restrict__ bias,
        float* __restrict__ Of32, f16* __restrict__ Ohi, f16* __restrict__ Olo,
        int M, int relu) {
    __shared__ __align__(16) f16 LA[3][2][4096];   // [buf][mat][row*64+slot*8] = 48KB
    int tid = threadIdx.x, w = tid >> 6, lane = tid & 63;
    int row0 = (int)blockIdx.x * 64;
    int m = lane & 31, kh = lane >> 5;
    const int T = 4;   // K=256 in 4 slabs of 64

    f32x16 acc[2][2] = {};   // [row-tile i][col-tile jt]

    {
        #define STAGE(t_, b_)                                                     \
        {                                                                         \
            int k0e_ = (t_) * 64;                                                 \
            int rl_ = lane >> 3;                                                  \
            int k8s_ = (lane & 7) ^ rl_;                                          \
            _Pragma("unroll")                                                     \
            for (int q = 0; q < 4; ++q) {                                         \
                int o_ = w * 4 + q;                                               \
                int mat_ = o_ >> 3, rg_ = o_ & 7;                                 \
                int r_ = row0 + rg_ * 8 + rl_;                                    \
                if (r_ >= M) r_ = M - 1;                                          \
                const f16* base_ = mat_ ? Alo : Ahi;                              \
                const f16* g_ = base_ + (size_t)r_ * 256 + k0e_ + k8s_ * 8;       \
                gload_lds16(g_, &LA[b_][mat_][rg_ * 512]);                        \
            }                                                                     \
        }
        STAGE(0, 0);
        STAGE(1, 1);
        asm volatile("s_waitcnt vmcnt(0)" ::: "memory");
        __builtin_amdgcn_s_barrier();
        __builtin_amdgcn_sched_barrier(0);
        for (int t = 0; t < T; ++t) {
            int b = t % 3;
            int k0e = t * 64;
            f16x8 Bh[4][2], Bl[4][2];
            #pragma unroll
            for (int jt = 0; jt < 2; ++jt) {
                int nn = w * 64 + jt * 32 + m;
                size_t boff = (size_t)nn * 256 + k0e + kh * 8;
                const f16* ph = Wth + boff;
                const f16* pl = Wtl + boff;
                #pragma unroll
                for (int s = 0; s < 4; ++s) {
                    Bh[s][jt] = *(const f16x8*)(ph + s * 16);
                    Bl[s][jt] = *(const f16x8*)(pl + s * 16);
                }
            }
            __builtin_amdgcn_sched_barrier(0);
            if (t + 2 < T) STAGE(t + 2, (t + 2) % 3);
            __builtin_amdgcn_sched_barrier(0);
            #pragma unroll
            for (int s = 0; s < 4; ++s) {
                int k8 = s * 2 + kh;
                int slot = (k8 ^ (m & 7)) * 8;
                f16x8 ah[2], al[2];
                #pragma unroll
                for (int i = 0; i < 2; ++i) {
                    int ro = (i * 32 + m) * 64;
                    ah[i] = *(const f16x8*)&LA[b][0][ro + slot];
                    al[i] = *(const f16x8*)&LA[b][1][ro + slot];
                }
                #pragma unroll
                for (int jt = 0; jt < 2; ++jt) {
                    #pragma unroll
                    for (int i = 0; i < 2; ++i) {
                        acc[i][jt] = MFMA(ah[i], Bh[s][jt], acc[i][jt]);
                        acc[i][jt] = MFMA(ah[i], Bl[s][jt], acc[i][jt]);
                        acc[i][jt] = MFMA(al[i], Bh[s][jt], acc[i][jt]);
                    }
                }
            }
            if (t + 2 < T) {
                asm volatile("s_waitcnt vmcnt(4)" ::: "memory");
            } else {
                asm volatile("s_waitcnt vmcnt(0)" ::: "memory");
            }
            __builtin_amdgcn_s_barrier();
            __builtin_amdgcn_sched_barrier(0);
        }
        #undef STAGE
    }

    #pragma unroll
    for (int jt = 0; jt < 2; ++jt) {
        int col = w * 64 + jt * 32 + m;
        float bv = bias[col];
        #pragma unroll
        for (int i = 0; i < 2; ++i) {
            #pragma unroll
            for (int r = 0; r < 16; ++r) {
                int row = row0 + i * 32 + (r & 3) + 8 * (r >> 2) + 4 * kh;
                if (row < M) {
                    float v = acc[i][jt][r] + bv;
                    if (relu) v = fmaxf(v, 0.f);
                    size_t idx = (size_t)row * 256 + col;
                    if (Of32) Of32[idx] = v;
                    if (Ohi) {
                        f16 h = (f16)v;
                        Ohi[idx] = h; Olo[idx] = (f16)(v - (float)h);
                    }
                }
            }
        }
    }
}

// ---------------- ctx GEMM: 8-wave / 512-thread, 2-buffer, max-TLP ------
// Same 64x256 tile and coalesced+XOR STAGE as R9, but 8 waves (one 32-col
// tile each: half the per-wave B-serial work) and 2 LDS buffers (35KB) ->
// ~24-32 waves/CU vs 12 before. Tests the TLP limit at fixed gather traffic.

__global__ __launch_bounds__(512) void ctx_gemm(
        const f16* __restrict__ fhi, const f16* __restrict__ flo,
        const int* __restrict__ perm, const int* __restrict__ plen,
        const int* __restrict__ label,
        const f16* __restrict__ Rth, const f16* __restrict__ Rtl,  // [256][2048] n-major
        const float* __restrict__ rbias, float* __restrict__ out,
        const f16* __restrict__ zp, int M) {
    __shared__ __align__(16) f16 LA[2][2][4096];   // [buf][mat][row*64+slot*8] = 32KB
    __shared__ int s_lbl[8][64];
    __shared__ int s_perm[64];
    __shared__ int s_max;
    int tid = threadIdx.x, w = tid >> 6, lane = tid & 63;
    int row0 = (int)(gridDim.x - 1 - blockIdx.x) * 64;   // longest-context blocks first
    int m = lane & 31, kh = lane >> 5;

    if (tid == 0) s_max = 0;
    __syncthreads();
    if (tid < 64) {
        int r = row0 + tid;
        int p = (r < M) ? perm[r] : -1;
        s_perm[tid] = p;
        int len = (r < M) ? plen[r] : 0;
        atomicMax(&s_max, len);
        int4 l0 = make_int4(-1, -1, -1, -1), l1 = l0;
        if (p >= 0) {
            l0 = *(const int4*)(label + (size_t)p * 8);
            l1 = *(const int4*)(label + (size_t)p * 8 + 4);
        }
        s_lbl[0][tid] = (0 < len) ? l0.x : -1;
        s_lbl[1][tid] = (1 < len) ? l0.y : -1;
        s_lbl[2][tid] = (2 < len) ? l0.z : -1;
        s_lbl[3][tid] = (3 < len) ? l0.w : -1;
        s_lbl[4][tid] = (4 < len) ? l1.x : -1;
        s_lbl[5][tid] = (5 < len) ? l1.y : -1;
        s_lbl[6][tid] = (6 < len) ? l1.z : -1;
        s_lbl[7][tid] = (7 < len) ? l1.w : -1;
    }
    __syncthreads();
    int T = s_max * 4;   // slabs: (j, k0/64)

    f32x16 acc[2] = {};   // [row-tile i], this wave's 32-col tile

    if (T > 0) {
        // stage slab t into buf b: 16 calls, wave w does w*2, w*2+1.
        // call o: mat=o>>3, rg=o&7 (rows rg*8..+7). lane l: row rg*8+(l>>3),
        // chunk (l&7)^(l>>3), linear LDS dest rg*512 + l*8.
        #define STAGE(t_, b_)                                                     \
        {                                                                         \
            int j_ = (t_) >> 2, k0e_ = ((t_) & 3) * 64;                           \
            int rl_ = lane >> 3;                                                  \
            int k8s_ = (lane & 7) ^ rl_;                                          \
            _Pragma("unroll")                                                     \
            for (int q = 0; q < 2; ++q) {                                         \
                int o_ = w * 2 + q;                                               \
                int mat_ = o_ >> 3, rg_ = o_ & 7;                                 \
                int lbl_ = s_lbl[j_][rg_ * 8 + rl_];                              \
                const f16* base_ = mat_ ? flo : fhi;                              \
                const f16* g_ = (lbl_ >= 0)                                       \
                    ? base_ + (size_t)lbl_ * 256 + k0e_ + k8s_ * 8 : zp;          \
                gload_lds16(g_, &LA[b_][mat_][rg_ * 512]);                        \
            }                                                                     \
        }
        STAGE(0, 0);
        __syncthreads();
        for (int t = 0; t < T; ++t) {
            if (t + 1 < T) STAGE(t + 1, (t + 1) & 1);
            int b = t & 1;
            int j = t >> 2, k0e = (t & 3) * 64;
            int nn = w * 32 + m;
            size_t boff = (size_t)nn * 2048 + j * 256 + k0e + kh * 8;
            const f16* pBh = Rth + boff;
            const f16* pBl = Rtl + boff;
            #pragma unroll
            for (int s = 0; s < 4; ++s) {
                int k8 = s * 2 + kh;
                int slot = (k8 ^ (m & 7)) * 8;
                f16x8 ah[2], al[2];
                #pragma unroll
                for (int i = 0; i < 2; ++i) {
                    int ro = (i * 32 + m) * 64;
                    ah[i] = *(const f16x8*)&LA[b][0][ro + slot];
                    al[i] = *(const f16x8*)&LA[b][1][ro + slot];
                }
                f16x8 bh = *(const f16x8*)(pBh + s * 16);
                f16x8 bl = *(const f16x8*)(pBl + s * 16);
                #pragma unroll
                for (int i = 0; i < 2; ++i) {
                    acc[i] = MFMA(ah[i], bh, acc[i]);
                    acc[i] = MFMA(ah[i], bl, acc[i]);
                    acc[i] = MFMA(al[i], bh, acc[i]);
                }
            }
            __syncthreads();
        }
        #undef STAGE
    }

    {
        int col = w * 32 + m;
        float rbv = rbias[col];
        #pragma unroll
        for (int i = 0; i < 2; ++i) {
            #pragma unroll
            for (int r = 0; r < 16; ++r) {
                int lr = i * 32 + (r & 3) + 8 * (r >> 2) + 4 * kh;
                int p = s_perm[lr];
                if (p >= 0) {
                    size_t idx = (size_t)p * 256 + col;
                    float f2 = (float)fhi[idx] + (float)flo[idx];
                    out[idx] = f2 * (acc[i][r] + rbv);
                }
            }
        }
    }
}

// ---------------- launch ----------------

extern "C" void kernel_launch(void* const* d_in, const int* in_sizes, int n_in,
                              void* d_out, int out_size, void* d_ws, size_t ws_size,
                              hipStream_t stream) {
    const float* x    = (const float*)d_in[0];
    const int*   edge = (const int*)d_in[1];
    const int*   lbl  = (const int*)d_in[2];
    const int*   clen = (const int*)d_in[3];
    const float* gW   = (const float*)d_in[4];
    const float* gb   = (const float*)d_in[5];
    const float* rW   = (const float*)d_in[6];
    const float* rb   = (const float*)d_in[7];

    const int N = in_sizes[3];
    const int E = in_sizes[1] / 2;

    char* ws = (char*)d_ws;
    size_t off = 0;
    auto take = [&](size_t bytes) -> char* {
        char* p = ws + off;
        off = (off + bytes + 255) & ~(size_t)255;
        return p;
    };
    // small control block: bcnt[256] bbase[257] bfill[256] chist[16] chbase[16] chfill[16]
    int*   g_small  = (int*)take(1024 * sizeof(int));
    int*   g_bcnt   = g_small;
    int*   g_bbase  = g_small + 256;
    int*   g_bfill  = g_small + 520;
    int*   g_chist  = g_small + 776;
    int*   g_chbase = g_small + 792;
    int*   g_chfill = g_small + 808;
    int*   row_ptr = (int*)take((size_t)(N + 1) * sizeof(int));
    int*   ew      = (int*)take((size_t)E * sizeof(int));
    int*   perm    = (int*)take((size_t)N * sizeof(int));
    int*   plen    = (int*)take((size_t)N * sizeof(int));
    float* inv_s   = (float*)take((size_t)N * sizeof(float));
    f16*   zp      = (f16*)take(1024);
    f16*   Wth     = (f16*)take((size_t)256 * 256 * sizeof(f16));
    f16*   Wtl     = (f16*)take((size_t)256 * 256 * sizeof(f16));
    f16*   Rth     = (f16*)take((size_t)256 * 2048 * sizeof(f16));
    f16*   Rtl     = (f16*)take((size_t)256 * 2048 * sizeof(f16));
    f16*   Ahi     = (f16*)take((size_t)N * 256 * sizeof(f16));
    f16*   Alo     = (f16*)take((size_t)N * 256 * sizeof(f16));
    float* Y1      = (float*)take((size_t)N * 256 * sizeof(float));
    f16*   Fhi     = (f16*)take((size_t)N * 256 * sizeof(f16));
    f16*   Flo     = (f16*)take((size_t)N * 256 * sizeof(f16));
    int2*  binned  = (int2*)Y1;   // dead before Y1's first use (gemm1)

    hipMemsetAsync(g_small, 0, 1024 * sizeof(int), stream);
    hipMemsetAsync(zp, 0, 1024, stream);

    int NB   = (N + 255) >> 8;
    int GBIN = (E + CHUNK - 1) / CHUNK;
    int CHN  = (N + GBIN - 1) / GBIN;

    bin_count_trans<<<GBIN + 144, 256, 0, stream>>>(edge + E, clen, g_bcnt, g_chist,
                                                    E, N, CHN, GBIN,
                                                    gW, Wth, Wtl, rW, Rth, Rtl);
    scan_small<<<1, 256, 0, stream>>>(g_bcnt, g_bbase, g_chist, g_chbase, NB, E);
    bin_scatter<<<GBIN, 256, 0, stream>>>(edge, edge + E, clen, g_bbase, g_bfill,
                                          g_chbase, g_chfill, binned, perm, plen,
                                          E, N, CHN);
    csr_build<<<NB, 256, 0, stream>>>(binned, g_bbase, row_ptr, inv_s, ew, E, N);

    int gB64 = (N + 63) / 64;
    agg_split<<<(N + 3) / 4, 512, 0, stream>>>(x, ew, row_ptr, inv_s, Ahi, Alo, N);
    gemm_lds<<<gB64, 256, 0, stream>>>(Ahi, Alo, Wth, Wtl, gb, Y1, nullptr, nullptr, N, 1);
    agg_split<<<(N + 3) / 4, 512, 0, stream>>>(Y1, ew, row_ptr, inv_s, Ahi, Alo, N);
    gemm_lds<<<gB64, 256, 0, stream>>>(Ahi, Alo, Wth, Wtl, gb, nullptr, Fhi, Flo, N, 0);
    ctx_gemm<<<gB64, 512, 0, stream>>>(Fhi, Flo, perm, plen, lbl, Rth, Rtl,
                                       rb, (float*)d_out, zp, N);
}